// Round 3
// baseline (8628.513 us; speedup 1.0000x reference)
//
#include <hip/hip_runtime.h>
#include <cstdint>
#include <cstddef>

// ---------------- constants ----------------
constexpr int CB = 32;      // batch
constexpr int CS = 32;      // question seq
constexpr int CFL = 640;    // F*L
constexpr int CT = 24;      // steps

typedef __attribute__((ext_vector_type(8))) short short8;
typedef __attribute__((ext_vector_type(4))) float floatx4;
typedef __attribute__((ext_vector_type(8))) float float8;

// ---------------- helpers ----------------
__device__ __forceinline__ float bf2f(short s) {
  return __uint_as_float(((unsigned int)(unsigned short)s) << 16);
}
__device__ __forceinline__ short f2bf(float f) {
  unsigned int u = __float_as_uint(f);
  u = (u + 0x7FFFu + ((u >> 16) & 1u)) >> 16;
  return (short)u;
}
// exact split: f = hi + lo + O(2^-18 |f|)
__device__ __forceinline__ void split8(const float* __restrict__ p, short8& hi, short8& lo) {
#pragma unroll
  for (int j = 0; j < 8; ++j) {
    float f = p[j];
    short h = f2bf(f);
    hi[j] = h;
    lo[j] = f2bf(f - bf2f(h));
  }
}
__device__ __forceinline__ float sigf(float x) { return 1.f / (1.f + __expf(-x)); }
__device__ __forceinline__ float ftanh(float x) {
  float e = __expf(2.f * x);
  return 1.f - 2.f / (e + 1.f);
}

// ---------------- ws layout (bytes), total 71,516,160 B = 68.2 MiB ----------------
constexpr size_t OFF_FPROJ = 0;            // [20480][512] f32 = 41,943,040
constexpr size_t OFF_QPROJ = 41943040;     // [1024][512]  f32 =  2,097,152
constexpr size_t OFF_BTA   = 44040192;     // BTAh+BTAl [3072][512] bf16 pair = 6,291,456
constexpr size_t OFF_BTC   = 50331648;     // BTCh+BTCl [2048][1536] bf16 pair = 12,582,912
constexpr size_t OFF_ACT   = 62914560;     // [768][2560]  f32 = 7,864,320 (setup-alias: BTW1h/l bf16)
constexpr size_t OFF_HA    = 70778880;     // [32][3072]   f32 =    393,216
constexpr size_t OFF_H     = 71172096;     // [32][512]    f32 =     65,536
constexpr size_t OFF_XQ    = 71237632;     // [32][1024]   f32 =    131,072
constexpr size_t OFF_C     = 71368704;     // [32][512]    f32 =     65,536
constexpr size_t OFF_FS    = 71434240;     // [32][640]    f32 =     81,920 -> 71,516,160
// phase-2 (after recurrence; FPROJ/QPROJ/BTC dead):
constexpr size_t OFF_BTY   = 0;            // [32000][512] bf16 = 32,768,000
constexpr size_t OFF_BTR   = 32768000;     // BTRh+BTRl [1024][2560] bf16 pair = 10,485,760
constexpr size_t OFF_RBUF  = OFF_BTC;      // [768][1024]  f32  =  3,145,728
constexpr size_t OFF_MBUF  = OFF_BTC + 3145728;  // [768][512] bf16 = 786,432

// ---------------- manual grid barrier (device-scope, sense-reversing) ----------------
__device__ unsigned g_bar_cnt;
__device__ unsigned g_bar_gen;

__device__ __forceinline__ void grid_barrier(unsigned nblk) {
  __syncthreads();
  if (threadIdx.x == 0) {
    __threadfence();   // release
    unsigned g = __hip_atomic_load(&g_bar_gen, __ATOMIC_RELAXED, __HIP_MEMORY_SCOPE_AGENT);
    unsigned a = __hip_atomic_fetch_add(&g_bar_cnt, 1u, __ATOMIC_ACQ_REL, __HIP_MEMORY_SCOPE_AGENT);
    if (a == nblk - 1u) {
      __hip_atomic_store(&g_bar_cnt, 0u, __ATOMIC_RELAXED, __HIP_MEMORY_SCOPE_AGENT);
      __hip_atomic_store(&g_bar_gen, g + 1u, __ATOMIC_RELEASE, __HIP_MEMORY_SCOPE_AGENT);
    } else {
      while (__hip_atomic_load(&g_bar_gen, __ATOMIC_ACQUIRE, __HIP_MEMORY_SCOPE_AGENT) == g) {
        __builtin_amdgcn_s_sleep(1);
      }
    }
    __threadfence();   // acquire
  }
  __syncthreads();
}

// ---------------- init: zero h, c and barrier cells ----------------
__global__ void init_kernel(float* h, float* c_buf) {
  int i = blockIdx.x * 256 + threadIdx.x;
  if (i < 16384) { h[i] = 0.f; c_buf[i] = 0.f; }
  if (i == 0) { g_bar_cnt = 0u; g_bar_gen = 0u; }
}

// ---------------- gather prev tokens into act_all cols [512,1024) ----------------
__global__ void gather_prev_kernel(const int* __restrict__ target, const float* __restrict__ emb,
                                   float* __restrict__ act_all) {
  int r = blockIdx.x;            // 0..767 = t*32+b
  int t = r >> 5, b = r & 31;
  int tok = (t == 0) ? -1 : target[b * CT + (t - 1)];
  for (int e = threadIdx.x; e < 512; e += 256) {
    float v = (tok < 0) ? 0.f : emb[(size_t)tok * 512 + e];
    act_all[(size_t)r * 2560 + 512 + e] = v;
  }
}

// ---------------- fp32 transpose + hi/lo bf16 pre-split (optional gate-permute of rows) ----------------
__global__ __launch_bounds__(256) void transpose_split_kernel(
    const float* __restrict__ src, int src_ld, int src_row0,
    short* __restrict__ dsth, short* __restrict__ dstl,
    int dst_ld, int dst_row0, int dst_col0, int perm) {
  __shared__ float tile[64][65];
  int n0 = blockIdx.x * 64, k0 = blockIdx.y * 64;
  for (int it = 0; it < 16; ++it) {
    int idx = threadIdx.x + it * 256;
    int kk = idx >> 6, nn = idx & 63;
    tile[kk][nn] = src[(size_t)(src_row0 + k0 + kk) * src_ld + n0 + nn];
  }
  __syncthreads();
  for (int it = 0; it < 16; ++it) {
    int idx = threadIdx.x + it * 256;
    int nn = idx >> 6, kk = idx & 63;
    float f = tile[kk][nn];
    short hv = f2bf(f);
    int r = n0 + nn;
    int pr = perm ? (((r & 511) << 2) | (r >> 9)) : r;   // gate-major -> unit-major*4+gate
    size_t o = (size_t)(dst_row0 + pr) * dst_ld + dst_col0 + k0 + kk;
    dsth[o] = hv;
    dstl[o] = f2bf(f - bf2f(hv));
  }
}

// ---------------- fp32 -> bf16 transpose (for Wy) ----------------
__global__ __launch_bounds__(256) void transpose_f2b_kernel(
    const float* __restrict__ src, int src_ld,
    short* __restrict__ dst, int dst_ld) {
  __shared__ float tile[64][65];
  int n0 = blockIdx.x * 64, k0 = blockIdx.y * 64;
  for (int it = 0; it < 16; ++it) {
    int idx = threadIdx.x + it * 256;
    int kk = idx >> 6, nn = idx & 63;
    tile[kk][nn] = src[(size_t)(k0 + kk) * src_ld + n0 + nn];
  }
  __syncthreads();
  for (int it = 0; it < 16; ++it) {
    int idx = threadIdx.x + it * 256;
    int nn = idx >> 6, kk = idx & 63;
    dst[(size_t)(n0 + nn) * dst_ld + k0 + kk] = f2bf(tile[kk][nn]);
  }
}

// ---------------- wide split GEMM, pre-split B: C[M,N] = A[M,K]f32 @ (BTh+BTl)[N,K]^T ----------------
// grid.x = M/32, grid.y = N/512; 256 threads = 4 waves; wave covers 128 cols, block 32 rows x 512 cols.
__global__ __launch_bounds__(256) void gemm_bsw_kernel(
    const float* __restrict__ A, const short* __restrict__ BTh, const short* __restrict__ BTl,
    float* __restrict__ C, int N, int K) {
  const int lane = threadIdx.x & 63;
  const int wave = threadIdx.x >> 6;
  const int quad = lane >> 4;
  const int l16 = lane & 15;
  const int m_base = blockIdx.x * 32;
  const int n_base = blockIdx.y * 512 + wave * 128;

  floatx4 acc[2][8];
#pragma unroll
  for (int mi = 0; mi < 2; ++mi)
#pragma unroll
    for (int ni = 0; ni < 8; ++ni) acc[mi][ni] = (floatx4){0.f, 0.f, 0.f, 0.f};

  const float* a0p = A + (size_t)(m_base + l16) * K + quad * 8;
  const float* a1p = a0p + (size_t)16 * K;
  const short* bhp = BTh + (size_t)(n_base + l16) * K + quad * 8;
  const short* blp = BTl + (size_t)(n_base + l16) * K + quad * 8;

  for (int k0 = 0; k0 < K; k0 += 32) {
    short8 a0h, a0l, a1h, a1l;
    split8(a0p + k0, a0h, a0l);
    split8(a1p + k0, a1h, a1l);
#pragma unroll
    for (int ni = 0; ni < 8; ++ni) {
      short8 bh = *(const short8*)(bhp + (size_t)(ni * 16) * K + k0);
      short8 bl = *(const short8*)(blp + (size_t)(ni * 16) * K + k0);
      acc[0][ni] = __builtin_amdgcn_mfma_f32_16x16x32_bf16(a0h, bh, acc[0][ni], 0, 0, 0);
      acc[0][ni] = __builtin_amdgcn_mfma_f32_16x16x32_bf16(a0l, bh, acc[0][ni], 0, 0, 0);
      acc[0][ni] = __builtin_amdgcn_mfma_f32_16x16x32_bf16(a0h, bl, acc[0][ni], 0, 0, 0);
      acc[1][ni] = __builtin_amdgcn_mfma_f32_16x16x32_bf16(a1h, bh, acc[1][ni], 0, 0, 0);
      acc[1][ni] = __builtin_amdgcn_mfma_f32_16x16x32_bf16(a1l, bh, acc[1][ni], 0, 0, 0);
      acc[1][ni] = __builtin_amdgcn_mfma_f32_16x16x32_bf16(a1h, bl, acc[1][ni], 0, 0, 0);
    }
  }
#pragma unroll
  for (int mi = 0; mi < 2; ++mi)
#pragma unroll
    for (int ni = 0; ni < 8; ++ni) {
      int col = n_base + ni * 16 + l16;
#pragma unroll
      for (int r = 0; r < 4; ++r) {
        int row = m_base + mi * 16 + quad * 4 + r;
        C[(size_t)row * N + col] = acc[mi][ni][r];
      }
    }
}

// ---------------- shared memory for the persistent kernel ----------------
struct SharedBC {
  float fs_l[640];
  int   list_idx[64];
  float list_w[64];
  float qs_l[32];
  float qw_l[32];
};
union SharedU {
  float zsum[8][32][32];   // phases A and D (32 KB)
  SharedBC bc;             // phase C
};

// ---------------- persistent recurrence kernel: 256 blocks x 512 threads ----------------
// Per step: A (96 blk, hA GEMM K-split) | B (256 blk, fact scores) |
//           C (32 blk, select+softmax+fvec/qvec) | D (64 blk, gates GEMM K-split + cell)
__global__ __launch_bounds__(512, 2) void recurrence_kernel(
    const float* __restrict__ f_proj, const float* __restrict__ q_proj,
    const short* __restrict__ BTAh, const short* __restrict__ BTAl,
    const short* __restrict__ BTCh, const short* __restrict__ BTCl,
    const float* __restrict__ facts, const float* __restrict__ bq,
    const float* __restrict__ vq, const float* __restrict__ vf,
    const float* __restrict__ lstm_b,
    float* __restrict__ hA, float* __restrict__ h_buf, float* __restrict__ c_buf,
    float* __restrict__ xq, float* __restrict__ fs_buf, float* __restrict__ act_all) {
  __shared__ SharedU sm;
  const int bid = blockIdx.x;
  const int tid = threadIdx.x;
  const int lane = tid & 63;
  const int wave = tid >> 6;     // 0..7
  const int quad = lane >> 4;
  const int l16 = lane & 15;

#pragma unroll 1
  for (int t = 0; t < CT; ++t) {
    // ===== phase A: hA[32,3072] = h @ BTA^T; 96 blocks, 8-way K-split =====
    if (bid < 96) {
      const int n0 = bid * 32;
      const int kb = wave * 64;
      floatx4 acc[2][2];
#pragma unroll
      for (int mi = 0; mi < 2; ++mi)
#pragma unroll
        for (int ni = 0; ni < 2; ++ni) acc[mi][ni] = (floatx4){0.f, 0.f, 0.f, 0.f};
      const float* a0p = h_buf + (size_t)l16 * 512 + kb + quad * 8;
      const float* a1p = a0p + (size_t)16 * 512;
      const short* bhp = BTAh + (size_t)(n0 + l16) * 512 + kb + quad * 8;
      const short* blp = BTAl + (size_t)(n0 + l16) * 512 + kb + quad * 8;
#pragma unroll
      for (int k0 = 0; k0 < 64; k0 += 32) {
        short8 a0h, a0l, a1h, a1l;
        split8(a0p + k0, a0h, a0l);
        split8(a1p + k0, a1h, a1l);
#pragma unroll
        for (int ni = 0; ni < 2; ++ni) {
          short8 bh = *(const short8*)(bhp + (size_t)(ni * 16) * 512 + k0);
          short8 bl = *(const short8*)(blp + (size_t)(ni * 16) * 512 + k0);
          acc[0][ni] = __builtin_amdgcn_mfma_f32_16x16x32_bf16(a0h, bh, acc[0][ni], 0, 0, 0);
          acc[0][ni] = __builtin_amdgcn_mfma_f32_16x16x32_bf16(a0l, bh, acc[0][ni], 0, 0, 0);
          acc[0][ni] = __builtin_amdgcn_mfma_f32_16x16x32_bf16(a0h, bl, acc[0][ni], 0, 0, 0);
          acc[1][ni] = __builtin_amdgcn_mfma_f32_16x16x32_bf16(a1h, bh, acc[1][ni], 0, 0, 0);
          acc[1][ni] = __builtin_amdgcn_mfma_f32_16x16x32_bf16(a1l, bh, acc[1][ni], 0, 0, 0);
          acc[1][ni] = __builtin_amdgcn_mfma_f32_16x16x32_bf16(a1h, bl, acc[1][ni], 0, 0, 0);
        }
      }
#pragma unroll
      for (int mi = 0; mi < 2; ++mi)
#pragma unroll
        for (int ni = 0; ni < 2; ++ni) {
#pragma unroll
          for (int r = 0; r < 4; ++r)
            sm.zsum[wave][mi * 16 + quad * 4 + r][ni * 16 + l16] = acc[mi][ni][r];
        }
      __syncthreads();
      for (int o = tid; o < 1024; o += 512) {
        int bb = o >> 5, c = o & 31;
        float s = 0.f;
#pragma unroll
        for (int w = 0; w < 8; ++w) s += sm.zsum[w][bb][c];
        hA[(size_t)bb * 3072 + n0 + c] = s;
      }
    }
    grid_barrier(256);

    // ===== phase B: fact scores on all 256 blocks (80 rows/block, 10 rows/wave) =====
    {
      const int b = bid >> 3;
      const int row0 = (bid & 7) * 80 + wave * 10;
      float hf8[8], vf8r[8];
      const float* hp = hA + b * 3072 + 512 + lane * 8;
#pragma unroll
      for (int j = 0; j < 8; ++j) hf8[j] = hp[j];
      const float* vp = vf + lane * 8;
#pragma unroll
      for (int j = 0; j < 8; ++j) vf8r[j] = vp[j];
      const float* base = f_proj + ((size_t)(b * CFL + row0)) * 512 + lane * 8;
      float* fsp = fs_buf + b * CFL + row0;

      float8 A0 = *(const float8*)(base);
      float8 A1 = *(const float8*)(base + 512);
#pragma unroll
      for (int ii = 0; ii < 10; ii += 2) {
        float8 N0, N1;
        if (ii + 2 < 10) N0 = *(const float8*)(base + (size_t)(ii + 2) * 512);
        if (ii + 3 < 10) N1 = *(const float8*)(base + (size_t)(ii + 3) * 512);
        float s0 = 0.f;
#pragma unroll
        for (int j = 0; j < 8; ++j) s0 += ftanh(A0[j] + hf8[j]) * vf8r[j];
        for (int off = 32; off; off >>= 1) s0 += __shfl_xor(s0, off);
        if (lane == 0) fsp[ii] = s0;
        float s1 = 0.f;
#pragma unroll
        for (int j = 0; j < 8; ++j) s1 += ftanh(A1[j] + hf8[j]) * vf8r[j];
        for (int off = 32; off; off >>= 1) s1 += __shfl_xor(s1, off);
        if (lane == 0) fsp[ii + 1] = s1;
        if (ii + 2 < 10) A0 = N0;
        if (ii + 3 < 10) A1 = N1;
      }
    }
    grid_barrier(256);

    // ===== phase C: select + softmaxes + fvec + qvec (32 blocks) =====
    if (bid < 32) {
      const int b = bid;
      if (wave == 0) {
        float fsv[10];
        unsigned int keys[10];
#pragma unroll
        for (int c = 0; c < 10; ++c) {
          float v = fs_buf[b * CFL + c * 64 + lane];
          fsv[c] = v;
          sm.bc.fs_l[c * 64 + lane] = v;
          unsigned int u = __float_as_uint(v);
          keys[c] = (u & 0x80000000u) ? ~u : (u | 0x80000000u);
        }
        sm.bc.list_idx[lane] = lane;   // defensive prefill
        float lmax = fsv[0];
#pragma unroll
        for (int c = 1; c < 10; ++c) lmax = fmaxf(lmax, fsv[c]);
        for (int off = 32; off; off >>= 1) lmax = fmaxf(lmax, __shfl_xor(lmax, off));
        float maxv = lmax;

        unsigned int lo = 0u, hi = 0xFFFFFFFFu;
        for (int iter = 0; iter < 32; ++iter) {
          unsigned int span = hi - lo;
          unsigned int mid = lo + (span >> 1) + (span & 1u);
          int cnt = 0;
#pragma unroll
          for (int c = 0; c < 10; ++c) cnt += (keys[c] >= mid) ? 1 : 0;
          for (int off = 32; off; off >>= 1) cnt += __shfl_xor(cnt, off);
          if (cnt >= 64) lo = mid; else hi = mid - 1u;
        }
        unsigned int tau = lo;
        int cg_ = 0;
#pragma unroll
        for (int c = 0; c < 10; ++c) cg_ += (keys[c] > tau) ? 1 : 0;
        for (int off = 32; off; off >>= 1) cg_ += __shfl_xor(cg_, off);
        int cnt_gt = cg_;
        int ties_take = 64 - cnt_gt;
        if (ties_take < 0) ties_take = 0;

        int ngt = 0, neq = 0;
#pragma unroll
        for (int c = 0; c < 10; ++c) {
          unsigned int k = keys[c];
          unsigned long long mgt = __ballot(k > tau);
          unsigned long long meq = __ballot(k == tau);
          unsigned long long below = (1ull << lane) - 1ull;
          if (k > tau) {
            int pos = ngt + __popcll(mgt & below);
            if (pos < 64) sm.bc.list_idx[pos] = c * 64 + lane;
          } else if (k == tau) {
            int er = neq + __popcll(meq & below);
            int pos = cnt_gt + er;
            if (er < ties_take && pos < 64) sm.bc.list_idx[pos] = c * 64 + lane;
          }
          ngt += __popcll(mgt);
          neq += __popcll(meq);
        }
        float v = sm.bc.fs_l[sm.bc.list_idx[lane]];
        float e = __expf(v - maxv);
        float s = e;
        for (int off = 32; off; off >>= 1) s += __shfl_xor(s, off);
        sm.bc.list_w[lane] = e / s;
      } else {
        float hq8[8], vq8[8];
        const float* hp = hA + b * 3072 + lane * 8;
#pragma unroll
        for (int j = 0; j < 8; ++j) hq8[j] = hp[j];
        const float* vp = vq + lane * 8;
#pragma unroll
        for (int j = 0; j < 8; ++j) vq8[j] = vp[j];
        for (int s = wave - 1; s < 32; s += 7) {
          const float* qp = q_proj + (size_t)(b * CS + s) * 512 + lane * 8;
          float acc = 0.f;
#pragma unroll
          for (int j = 0; j < 8; ++j) acc += ftanh(qp[j] + hq8[j]) * vq8[j];
          for (int off = 32; off; off >>= 1) acc += __shfl_xor(acc, off);
          if (lane == 0) sm.bc.qs_l[s] = acc;
        }
      }
      __syncthreads();
      if (wave == 0 && lane < 32) {
        float v = sm.bc.qs_l[lane];
        float m = v;
        for (int off = 16; off; off >>= 1) m = fmaxf(m, __shfl_xor(m, off));
        float e = __expf(v - m);
        float s = e;
        for (int off = 16; off; off >>= 1) s += __shfl_xor(s, off);
        sm.bc.qw_l[lane] = e / s;
      }
      __syncthreads();

      const int d = tid;   // 0..511
      float f0 = 0.f;
      for (int j = 0; j < 64; ++j) {
        int idx = sm.bc.list_idx[j];
        float w = sm.bc.list_w[j];
        f0 += w * facts[((size_t)(b * CFL + idx)) * 512 + d];
      }
      const int row = t * CB + b;
      xq[b * 1024 + d] = f0;
      act_all[(size_t)row * 2560 + 1024 + d] = f0;

      float q0 = 0.f;
      for (int s = 0; s < 32; ++s) {
        q0 += sm.bc.qw_l[s] * bq[((size_t)(b * CS + s)) * 512 + d];
      }
      xq[b * 1024 + 512 + d] = q0;
      act_all[(size_t)row * 2560 + 1536 + d] = q0;
      act_all[(size_t)row * 2560 + 2048 + d] = q0;
    }
    grid_barrier(256);

    // ===== phase D: gates GEMM (gate-permuted cols) + cell update; 64 blocks, 8-way K-split =====
    if (bid < 64) {
      const int n0 = bid * 32;        // permuted col space: unit = (n0+c)>>2, gate = (n0+c)&3
      const int kb = wave * 192;
      floatx4 acc[2][2];
#pragma unroll
      for (int mi = 0; mi < 2; ++mi)
#pragma unroll
        for (int ni = 0; ni < 2; ++ni) acc[mi][ni] = (floatx4){0.f, 0.f, 0.f, 0.f};
      const short* bhp = BTCh + (size_t)(n0 + l16) * 1536 + kb + quad * 8;
      const short* blp = BTCl + (size_t)(n0 + l16) * 1536 + kb + quad * 8;
#pragma unroll 1
      for (int s6 = 0; s6 < 6; ++s6) {
        int k0 = kb + s6 * 32;
        const float *a0p, *a1p;
        if (k0 < 1024) {
          a0p = xq + (size_t)l16 * 1024 + k0 + quad * 8;
          a1p = a0p + (size_t)16 * 1024;
        } else {
          a0p = act_all + (size_t)(t * CB + l16) * 2560 + 512 + (k0 - 1024) + quad * 8;
          a1p = a0p + (size_t)16 * 2560;
        }
        short8 a0h, a0l, a1h, a1l;
        split8(a0p, a0h, a0l);
        split8(a1p, a1h, a1l);
#pragma unroll
        for (int ni = 0; ni < 2; ++ni) {
          short8 bh = *(const short8*)(bhp + (size_t)(ni * 16) * 1536 + s6 * 32);
          short8 bl = *(const short8*)(blp + (size_t)(ni * 16) * 1536 + s6 * 32);
          acc[0][ni] = __builtin_amdgcn_mfma_f32_16x16x32_bf16(a0h, bh, acc[0][ni], 0, 0, 0);
          acc[0][ni] = __builtin_amdgcn_mfma_f32_16x16x32_bf16(a0l, bh, acc[0][ni], 0, 0, 0);
          acc[0][ni] = __builtin_amdgcn_mfma_f32_16x16x32_bf16(a0h, bl, acc[0][ni], 0, 0, 0);
          acc[1][ni] = __builtin_amdgcn_mfma_f32_16x16x32_bf16(a1h, bh, acc[1][ni], 0, 0, 0);
          acc[1][ni] = __builtin_amdgcn_mfma_f32_16x16x32_bf16(a1l, bh, acc[1][ni], 0, 0, 0);
          acc[1][ni] = __builtin_amdgcn_mfma_f32_16x16x32_bf16(a1h, bl, acc[1][ni], 0, 0, 0);
        }
      }
#pragma unroll
      for (int mi = 0; mi < 2; ++mi)
#pragma unroll
        for (int ni = 0; ni < 2; ++ni) {
#pragma unroll
          for (int r = 0; r < 4; ++r)
            sm.zsum[wave][mi * 16 + quad * 4 + r][ni * 16 + l16] = acc[mi][ni][r];
        }
      __syncthreads();

      if (tid < 256) {
        int bb = tid >> 3, ul = tid & 7;
        int u = (n0 >> 2) + ul;
        float z[4];
#pragma unroll
        for (int g = 0; g < 4; ++g) {
          int c = ul * 4 + g;
          float s = 0.f;
#pragma unroll
          for (int w = 0; w < 8; ++w) s += sm.zsum[w][bb][c];
          z[g] = s + hA[(size_t)bb * 3072 + 1024 + n0 + c] + lstm_b[g * 512 + u];
        }
        int ci = bb * 512 + u;
        float cold = c_buf[ci];
        float c2 = sigf(z[1]) * cold + sigf(z[0]) * ftanh(z[2]);
        float h2 = sigf(z[3]) * ftanh(c2);
        c_buf[ci] = c2;
        h_buf[ci] = h2;
        act_all[(size_t)(t * CB + bb) * 2560 + u] = h2;
      }
    }
    grid_barrier(256);
  }
}

// ---------------- maxout (+ biases) ----------------
__global__ void maxout_kernel(const float* __restrict__ R, const float* __restrict__ br,
                              const float* __restrict__ bur, const float* __restrict__ bvr,
                              short* __restrict__ m_buf) {
  int idx = blockIdx.x * 256 + threadIdx.x;  // < 768*512
  int r = idx >> 9, j = idx & 511;
  int n0 = j * 2, n1 = j * 2 + 1;
  float v0 = R[(size_t)r * 1024 + n0] + br[n0] + bur[n0] + bvr[n0];
  float v1 = R[(size_t)r * 1024 + n1] + br[n1] + bur[n1] + bvr[n1];
  m_buf[(size_t)r * 512 + j] = f2bf(fmaxf(v0, v1));
}

// ---------------- logits GEMM: bf16 A,B -> f32 out + f32 bias ----------------
__global__ __launch_bounds__(256) void gemm_bf_kernel(
    const short* __restrict__ A, const short* __restrict__ BT,
    float* __restrict__ C, const float* __restrict__ bias, int N, int K) {
  const int lane = threadIdx.x & 63;
  const int wave = threadIdx.x >> 6;
  const int quad = lane >> 4;
  const int l16 = lane & 15;
  const int m_base = blockIdx.x * 64 + (wave & 1) * 32;
  const int n_base = blockIdx.y * 128 + (wave >> 1) * 64;

  floatx4 acc[2][4];
#pragma unroll
  for (int mi = 0; mi < 2; ++mi)
#pragma unroll
    for (int ni = 0; ni < 4; ++ni) acc[mi][ni] = (floatx4){0.f, 0.f, 0.f, 0.f};

  const short* a0p = A + (size_t)(m_base + l16) * K + quad * 8;
  const short* a1p = a0p + (size_t)16 * K;
  const short* b0p = BT + (size_t)(n_base + l16) * K + quad * 8;

  for (int k0 = 0; k0 < K; k0 += 32) {
    short8 a0 = *(const short8*)(a0p + k0);
    short8 a1 = *(const short8*)(a1p + k0);
#pragma unroll
    for (int ni = 0; ni < 4; ++ni) {
      short8 bb = *(const short8*)(b0p + (size_t)(ni * 16) * K + k0);
      acc[0][ni] = __builtin_amdgcn_mfma_f32_16x16x32_bf16(a0, bb, acc[0][ni], 0, 0, 0);
      acc[1][ni] = __builtin_amdgcn_mfma_f32_16x16x32_bf16(a1, bb, acc[1][ni], 0, 0, 0);
    }
  }
#pragma unroll
  for (int mi = 0; mi < 2; ++mi)
#pragma unroll
    for (int ni = 0; ni < 4; ++ni) {
      int col = n_base + ni * 16 + l16;
#pragma unroll
      for (int r = 0; r < 4; ++r) {
        int row = m_base + mi * 16 + quad * 4 + r;
        C[(size_t)row * N + col] = acc[mi][ni][r] + bias[col];
      }
    }
}

// ---------------- launch ----------------
extern "C" void kernel_launch(void* const* d_in, const int* in_sizes, int n_in,
                              void* d_out, int out_size, void* d_ws, size_t ws_size,
                              hipStream_t stream) {
  const float* bq     = (const float*)d_in[0];
  const float* facts  = (const float*)d_in[1];
  const int*   target = (const int*)d_in[2];
  const float* emb    = (const float*)d_in[4];
  const float* lstm_k = (const float*)d_in[5];
  const float* lstm_r = (const float*)d_in[6];
  const float* lstm_b = (const float*)d_in[7];
  const float* Wq1 = (const float*)d_in[8];
  const float* Wq2 = (const float*)d_in[9];
  const float* vq  = (const float*)d_in[10];
  const float* Wf1 = (const float*)d_in[11];
  const float* Wf2 = (const float*)d_in[12];
  const float* vf  = (const float*)d_in[13];
  const float* Wr  = (const float*)d_in[14];
  const float* br  = (const float*)d_in[15];
  const float* Ur  = (const float*)d_in[16];
  const float* bur = (const float*)d_in[17];
  const float* Vr  = (const float*)d_in[18];
  const float* bvr = (const float*)d_in[19];
  const float* Wy  = (const float*)d_in[20];
  const float* by  = (const float*)d_in[21];

  char* ws = (char*)d_ws;
  float* f_proj  = (float*)(ws + OFF_FPROJ);
  float* q_proj  = (float*)(ws + OFF_QPROJ);
  short* BTAh    = (short*)(ws + OFF_BTA);
  short* BTAl    = BTAh + (size_t)3072 * 512;
  short* BTCh    = (short*)(ws + OFF_BTC);
  short* BTCl    = BTCh + (size_t)2048 * 1536;
  float* act_all = (float*)(ws + OFF_ACT);
  short* BTW1h   = (short*)(ws + OFF_ACT);            // setup-phase alias (dies before gather_prev)
  short* BTW1l   = BTW1h + (size_t)512 * 512;
  float* hA      = (float*)(ws + OFF_HA);
  float* h_buf   = (float*)(ws + OFF_H);
  float* xq      = (float*)(ws + OFF_XQ);
  float* c_buf   = (float*)(ws + OFF_C);
  float* fs_buf  = (float*)(ws + OFF_FS);
  short* BTY     = (short*)(ws + OFF_BTY);
  short* BTRh    = (short*)(ws + OFF_BTR);
  short* BTRl    = BTRh + (size_t)1024 * 2560;
  float* R_buf   = (float*)(ws + OFF_RBUF);
  short* m_buf   = (short*)(ws + OFF_MBUF);
  float* out     = (float*)d_out;

  auto TS = [&](const float* src, int sld, int srow0, short* dh, short* dl, int dld,
                int drow0, int dcol0, int NR, int NK, int perm) {
    transpose_split_kernel<<<dim3(NR / 64, NK / 64), 256, 0, stream>>>(
        src, sld, srow0, dh, dl, dld, drow0, dcol0, perm);
  };

  // --- persistent transposed + pre-split weights (bf16 hi/lo) ---
  TS(Wq2, 512, 0, BTAh, BTAl, 512, 0, 0, 512, 512, 0);
  TS(Wf2, 512, 0, BTAh, BTAl, 512, 512, 0, 512, 512, 0);
  TS(lstm_r, 2048, 0, BTAh, BTAl, 512, 1024, 0, 2048, 512, 1);         // gate-permuted
  TS(lstm_k, 2048, 512, BTCh, BTCl, 1536, 0, 0, 2048, 512, 1);         // fvec K-part, permuted
  TS(lstm_k, 2048, 1024, BTCh, BTCl, 1536, 0, 512, 2048, 512, 1);      // qvec K-part, permuted
  TS(lstm_k, 2048, 0, BTCh, BTCl, 1536, 0, 1024, 2048, 512, 1);        // prev K-part, permuted

  // --- hoisted projections (BTW1 aliases act_all; used before gather_prev) ---
  TS(Wq1, 512, 0, BTW1h, BTW1l, 512, 0, 0, 512, 512, 0);
  gemm_bsw_kernel<<<dim3(32, 1), 256, 0, stream>>>(bq, BTW1h, BTW1l, q_proj, 512, 512);
  TS(Wf1, 512, 0, BTW1h, BTW1l, 512, 0, 0, 512, 512, 0);
  gemm_bsw_kernel<<<dim3(640, 1), 256, 0, stream>>>(facts, BTW1h, BTW1l, f_proj, 512, 512);

  // --- init recurrent state + barrier cells + prev tokens ---
  init_kernel<<<64, 256, 0, stream>>>(h_buf, c_buf);
  gather_prev_kernel<<<768, 256, 0, stream>>>(target, emb, act_all);

  // --- recurrence: persistent kernel, full grid, 4 device barriers per step ---
  recurrence_kernel<<<256, 512, 0, stream>>>(f_proj, q_proj, BTAh, BTAl, BTCh, BTCl,
                                             facts, bq, vq, vf, lstm_b,
                                             hA, h_buf, c_buf, xq, fs_buf, act_all);

  // --- end-stage weights into dead regions ---
  TS(Wr, 1024, 0, BTRh, BTRl, 2560, 0, 0, 1024, 512, 0);
  TS(Ur, 1024, 0, BTRh, BTRl, 2560, 0, 512, 1024, 1536, 0);
  TS(Vr, 1024, 0, BTRh, BTRl, 2560, 0, 2048, 1024, 512, 0);
  transpose_f2b_kernel<<<dim3(500, 8), 256, 0, stream>>>(Wy, 32000, BTY, 512);

  // --- batched readout + maxout + logits ---
  gemm_bsw_kernel<<<dim3(24, 2), 256, 0, stream>>>(act_all, BTRh, BTRl, R_buf, 1024, 2560);
  maxout_kernel<<<1536, 256, 0, stream>>>(R_buf, br, bur, bvr, m_buf);
  gemm_bf_kernel<<<dim3(12, 250), 256, 0, stream>>>(m_buf, BTY, out, by, 32000, 512);
}

// Round 4
// 8408.278 us; speedup vs baseline: 1.0262x; 1.0262x over previous
//
#include <hip/hip_runtime.h>
#include <cstdint>
#include <cstddef>

// ---------------- constants ----------------
constexpr int CB = 32;      // batch
constexpr int CS = 32;      // question seq
constexpr int CFL = 640;    // F*L
constexpr int CT = 24;      // steps
constexpr int NBLK = 256;   // persistent grid size

typedef __attribute__((ext_vector_type(8))) short short8;
typedef __attribute__((ext_vector_type(4))) float floatx4;
typedef __attribute__((ext_vector_type(8))) float float8;

// ---------------- helpers ----------------
__device__ __forceinline__ float bf2f(short s) {
  return __uint_as_float(((unsigned int)(unsigned short)s) << 16);
}
__device__ __forceinline__ short f2bf(float f) {
  unsigned int u = __float_as_uint(f);
  u = (u + 0x7FFFu + ((u >> 16) & 1u)) >> 16;
  return (short)u;
}
// exact split: f = hi + lo + O(2^-18 |f|)
__device__ __forceinline__ void split8(const float* __restrict__ p, short8& hi, short8& lo) {
#pragma unroll
  for (int j = 0; j < 8; ++j) {
    float f = p[j];
    short h = f2bf(f);
    hi[j] = h;
    lo[j] = f2bf(f - bf2f(h));
  }
}
__device__ __forceinline__ float sigf(float x) { return 1.f / (1.f + __expf(-x)); }
__device__ __forceinline__ float ftanh(float x) {
  float e = __expf(2.f * x);
  return 1.f - 2.f / (e + 1.f);
}

// ---------------- ws layout (bytes), total 71,516,160 B = 68.2 MiB ----------------
constexpr size_t OFF_FPROJ = 0;            // [20480][512] f32 = 41,943,040
constexpr size_t OFF_QPROJ = 41943040;     // [1024][512]  f32 =  2,097,152
constexpr size_t OFF_BTA   = 44040192;     // BTAh+BTAl [3072][512] bf16 pair = 6,291,456
constexpr size_t OFF_BTC   = 50331648;     // BTCh+BTCl [2048][1536] bf16 pair = 12,582,912
constexpr size_t OFF_ACT   = 62914560;     // [768][2560]  f32 = 7,864,320 (setup-alias: BTW1h/l bf16)
constexpr size_t OFF_HA    = 70778880;     // [32][3072]   f32 =    393,216
constexpr size_t OFF_H     = 71172096;     // [32][512]    f32 =     65,536
constexpr size_t OFF_XQ    = 71237632;     // [32][1024]   f32 =    131,072
constexpr size_t OFF_C     = 71368704;     // [32][512]    f32 =     65,536
constexpr size_t OFF_FS    = 71434240;     // [32][640]    f32 =     81,920 -> 71,516,160
// phase-2 (after recurrence; FPROJ/QPROJ/BTC dead):
constexpr size_t OFF_BTY   = 0;            // [32000][512] bf16 = 32,768,000
constexpr size_t OFF_BTR   = 32768000;     // BTRh+BTRl [1024][2560] bf16 pair = 10,485,760
constexpr size_t OFF_RBUF  = OFF_BTC;      // [768][1024]  f32  =  3,145,728
constexpr size_t OFF_MBUF  = OFF_BTC + 3145728;  // [768][512] bf16 = 786,432

// ---------------- flag-based grid barrier: parallel arrive, master aggregate ----------------
// No serialized RMW chain: each block STOREs its epoch into a padded slot; block 0's
// threads poll all slots in parallel; single release word.
__device__ unsigned g_arrive[NBLK * 16];   // 64B stride per block
__device__ unsigned g_epoch;

__device__ __forceinline__ void grid_barrier(int bid, int tid, unsigned ep) {
  __syncthreads();
  if (tid == 0) {
    __threadfence();   // release: my writes visible device-wide
    __hip_atomic_store(&g_arrive[bid * 16], ep, __ATOMIC_RELEASE, __HIP_MEMORY_SCOPE_AGENT);
  }
  if (bid == 0) {
    if (tid < NBLK) {
      while (__hip_atomic_load(&g_arrive[tid * 16], __ATOMIC_ACQUIRE, __HIP_MEMORY_SCOPE_AGENT) < ep) {
      }
    }
    __syncthreads();
    if (tid == 0) {
      __hip_atomic_store(&g_epoch, ep, __ATOMIC_RELEASE, __HIP_MEMORY_SCOPE_AGENT);
    }
  }
  if (tid == 0) {
    while (__hip_atomic_load(&g_epoch, __ATOMIC_ACQUIRE, __HIP_MEMORY_SCOPE_AGENT) < ep) {
      __builtin_amdgcn_s_sleep(1);
    }
    __threadfence();   // acquire: don't read stale data
  }
  __syncthreads();
}

// ---------------- init: zero h, c and barrier cells ----------------
__global__ void init_kernel(float* h, float* c_buf) {
  int i = blockIdx.x * 256 + threadIdx.x;
  if (i < 16384) { h[i] = 0.f; c_buf[i] = 0.f; }
  if (i < NBLK * 16) g_arrive[i] = 0u;
  if (i == 0) g_epoch = 0u;
}

// ---------------- gather prev tokens into act_all cols [512,1024) ----------------
__global__ void gather_prev_kernel(const int* __restrict__ target, const float* __restrict__ emb,
                                   float* __restrict__ act_all) {
  int r = blockIdx.x;            // 0..767 = t*32+b
  int t = r >> 5, b = r & 31;
  int tok = (t == 0) ? -1 : target[b * CT + (t - 1)];
  for (int e = threadIdx.x; e < 512; e += 256) {
    float v = (tok < 0) ? 0.f : emb[(size_t)tok * 512 + e];
    act_all[(size_t)r * 2560 + 512 + e] = v;
  }
}

// ---------------- fp32 transpose + hi/lo bf16 pre-split (optional gate-permute of rows) ----------------
__global__ __launch_bounds__(256) void transpose_split_kernel(
    const float* __restrict__ src, int src_ld, int src_row0,
    short* __restrict__ dsth, short* __restrict__ dstl,
    int dst_ld, int dst_row0, int dst_col0, int perm) {
  __shared__ float tile[64][65];
  int n0 = blockIdx.x * 64, k0 = blockIdx.y * 64;
  for (int it = 0; it < 16; ++it) {
    int idx = threadIdx.x + it * 256;
    int kk = idx >> 6, nn = idx & 63;
    tile[kk][nn] = src[(size_t)(src_row0 + k0 + kk) * src_ld + n0 + nn];
  }
  __syncthreads();
  for (int it = 0; it < 16; ++it) {
    int idx = threadIdx.x + it * 256;
    int nn = idx >> 6, kk = idx & 63;
    float f = tile[kk][nn];
    short hv = f2bf(f);
    int r = n0 + nn;
    int pr = perm ? (((r & 511) << 2) | (r >> 9)) : r;   // gate-major -> unit-major*4+gate
    size_t o = (size_t)(dst_row0 + pr) * dst_ld + dst_col0 + k0 + kk;
    dsth[o] = hv;
    dstl[o] = f2bf(f - bf2f(hv));
  }
}

// ---------------- fp32 -> bf16 transpose (for Wy) ----------------
__global__ __launch_bounds__(256) void transpose_f2b_kernel(
    const float* __restrict__ src, int src_ld,
    short* __restrict__ dst, int dst_ld) {
  __shared__ float tile[64][65];
  int n0 = blockIdx.x * 64, k0 = blockIdx.y * 64;
  for (int it = 0; it < 16; ++it) {
    int idx = threadIdx.x + it * 256;
    int kk = idx >> 6, nn = idx & 63;
    tile[kk][nn] = src[(size_t)(k0 + kk) * src_ld + n0 + nn];
  }
  __syncthreads();
  for (int it = 0; it < 16; ++it) {
    int idx = threadIdx.x + it * 256;
    int nn = idx >> 6, kk = idx & 63;
    dst[(size_t)(n0 + nn) * dst_ld + k0 + kk] = f2bf(tile[kk][nn]);
  }
}

// ---------------- wide split GEMM, pre-split B: C[M,N] = A[M,K]f32 @ (BTh+BTl)[N,K]^T ----------------
__global__ __launch_bounds__(256) void gemm_bsw_kernel(
    const float* __restrict__ A, const short* __restrict__ BTh, const short* __restrict__ BTl,
    float* __restrict__ C, int N, int K) {
  const int lane = threadIdx.x & 63;
  const int wave = threadIdx.x >> 6;
  const int quad = lane >> 4;
  const int l16 = lane & 15;
  const int m_base = blockIdx.x * 32;
  const int n_base = blockIdx.y * 512 + wave * 128;

  floatx4 acc[2][8];
#pragma unroll
  for (int mi = 0; mi < 2; ++mi)
#pragma unroll
    for (int ni = 0; ni < 8; ++ni) acc[mi][ni] = (floatx4){0.f, 0.f, 0.f, 0.f};

  const float* a0p = A + (size_t)(m_base + l16) * K + quad * 8;
  const float* a1p = a0p + (size_t)16 * K;
  const short* bhp = BTh + (size_t)(n_base + l16) * K + quad * 8;
  const short* blp = BTl + (size_t)(n_base + l16) * K + quad * 8;

  for (int k0 = 0; k0 < K; k0 += 32) {
    short8 a0h, a0l, a1h, a1l;
    split8(a0p + k0, a0h, a0l);
    split8(a1p + k0, a1h, a1l);
#pragma unroll
    for (int ni = 0; ni < 8; ++ni) {
      short8 bh = *(const short8*)(bhp + (size_t)(ni * 16) * K + k0);
      short8 bl = *(const short8*)(blp + (size_t)(ni * 16) * K + k0);
      acc[0][ni] = __builtin_amdgcn_mfma_f32_16x16x32_bf16(a0h, bh, acc[0][ni], 0, 0, 0);
      acc[0][ni] = __builtin_amdgcn_mfma_f32_16x16x32_bf16(a0l, bh, acc[0][ni], 0, 0, 0);
      acc[0][ni] = __builtin_amdgcn_mfma_f32_16x16x32_bf16(a0h, bl, acc[0][ni], 0, 0, 0);
      acc[1][ni] = __builtin_amdgcn_mfma_f32_16x16x32_bf16(a1h, bh, acc[1][ni], 0, 0, 0);
      acc[1][ni] = __builtin_amdgcn_mfma_f32_16x16x32_bf16(a1l, bh, acc[1][ni], 0, 0, 0);
      acc[1][ni] = __builtin_amdgcn_mfma_f32_16x16x32_bf16(a1h, bl, acc[1][ni], 0, 0, 0);
    }
  }
#pragma unroll
  for (int mi = 0; mi < 2; ++mi)
#pragma unroll
    for (int ni = 0; ni < 8; ++ni) {
      int col = n_base + ni * 16 + l16;
#pragma unroll
      for (int r = 0; r < 4; ++r) {
        int row = m_base + mi * 16 + quad * 4 + r;
        C[(size_t)row * N + col] = acc[mi][ni][r];
      }
    }
}

// ---------------- shared memory for the persistent kernel ----------------
struct SharedBC {
  float fs_l[640];
  int   list_idx[64];
  float list_w[64];
  float qs_l[32];
  float qw_l[32];
};
union SharedU {
  float zsum[8][32][33];   // phases A and D; [33] pad -> conflict-free partial-sum stores
  SharedBC bc;             // phase C
};

// ---------------- persistent recurrence kernel: 256 blocks x 512 threads ----------------
__global__ __launch_bounds__(512, 2) void recurrence_kernel(
    const float* __restrict__ f_proj, const float* __restrict__ q_proj,
    const short* __restrict__ BTAh, const short* __restrict__ BTAl,
    const short* __restrict__ BTCh, const short* __restrict__ BTCl,
    const float* __restrict__ facts, const float* __restrict__ bq,
    const float* __restrict__ vq, const float* __restrict__ vf,
    const float* __restrict__ lstm_b,
    float* __restrict__ hA, float* __restrict__ h_buf, float* __restrict__ c_buf,
    float* __restrict__ xq, float* __restrict__ fs_buf, float* __restrict__ act_all) {
  __shared__ SharedU sm;
  const int bid = blockIdx.x;
  const int tid = threadIdx.x;
  const int lane = tid & 63;
  const int wave = tid >> 6;     // 0..7
  const int quad = lane >> 4;
  const int l16 = lane & 15;
  unsigned ep = 0;

#pragma unroll 1
  for (int t = 0; t < CT; ++t) {
    // ===== phase A: hA[32,3072] = h @ BTA^T; 96 blocks, 8-way K-split =====
    if (bid < 96) {
      const int n0 = bid * 32;
      const int kb = wave * 64;
      floatx4 acc[2][2];
#pragma unroll
      for (int mi = 0; mi < 2; ++mi)
#pragma unroll
        for (int ni = 0; ni < 2; ++ni) acc[mi][ni] = (floatx4){0.f, 0.f, 0.f, 0.f};
      const float* a0p = h_buf + (size_t)l16 * 512 + kb + quad * 8;
      const float* a1p = a0p + (size_t)16 * 512;
      const short* bhp = BTAh + (size_t)(n0 + l16) * 512 + kb + quad * 8;
      const short* blp = BTAl + (size_t)(n0 + l16) * 512 + kb + quad * 8;
#pragma unroll
      for (int k0 = 0; k0 < 64; k0 += 32) {
        short8 a0h, a0l, a1h, a1l;
        split8(a0p + k0, a0h, a0l);
        split8(a1p + k0, a1h, a1l);
#pragma unroll
        for (int ni = 0; ni < 2; ++ni) {
          short8 bh = *(const short8*)(bhp + (size_t)(ni * 16) * 512 + k0);
          short8 bl = *(const short8*)(blp + (size_t)(ni * 16) * 512 + k0);
          acc[0][ni] = __builtin_amdgcn_mfma_f32_16x16x32_bf16(a0h, bh, acc[0][ni], 0, 0, 0);
          acc[0][ni] = __builtin_amdgcn_mfma_f32_16x16x32_bf16(a0l, bh, acc[0][ni], 0, 0, 0);
          acc[0][ni] = __builtin_amdgcn_mfma_f32_16x16x32_bf16(a0h, bl, acc[0][ni], 0, 0, 0);
          acc[1][ni] = __builtin_amdgcn_mfma_f32_16x16x32_bf16(a1h, bh, acc[1][ni], 0, 0, 0);
          acc[1][ni] = __builtin_amdgcn_mfma_f32_16x16x32_bf16(a1l, bh, acc[1][ni], 0, 0, 0);
          acc[1][ni] = __builtin_amdgcn_mfma_f32_16x16x32_bf16(a1h, bl, acc[1][ni], 0, 0, 0);
        }
      }
#pragma unroll
      for (int mi = 0; mi < 2; ++mi)
#pragma unroll
        for (int ni = 0; ni < 2; ++ni) {
#pragma unroll
          for (int r = 0; r < 4; ++r)
            sm.zsum[wave][mi * 16 + quad * 4 + r][ni * 16 + l16] = acc[mi][ni][r];
        }
      __syncthreads();
      for (int o = tid; o < 1024; o += 512) {
        int bb = o >> 5, c = o & 31;
        float s = 0.f;
#pragma unroll
        for (int w = 0; w < 8; ++w) s += sm.zsum[w][bb][c];
        hA[(size_t)bb * 3072 + n0 + c] = s;
      }
    }
    grid_barrier(bid, tid, ++ep);

    // ===== phase B: fact scores on all 256 blocks (80 rows/block, 10 rows/wave) =====
    {
      const int b = bid >> 3;
      const int row0 = (bid & 7) * 80 + wave * 10;
      float hf8[8], vf8r[8];
      const float* hp = hA + b * 3072 + 512 + lane * 8;
#pragma unroll
      for (int j = 0; j < 8; ++j) hf8[j] = hp[j];
      const float* vp = vf + lane * 8;
#pragma unroll
      for (int j = 0; j < 8; ++j) vf8r[j] = vp[j];
      const float* base = f_proj + ((size_t)(b * CFL + row0)) * 512 + lane * 8;
      float* fsp = fs_buf + b * CFL + row0;

      float8 A0 = *(const float8*)(base);
      float8 A1 = *(const float8*)(base + 512);
#pragma unroll
      for (int ii = 0; ii < 10; ii += 2) {
        float8 N0, N1;
        if (ii + 2 < 10) N0 = *(const float8*)(base + (size_t)(ii + 2) * 512);
        if (ii + 3 < 10) N1 = *(const float8*)(base + (size_t)(ii + 3) * 512);
        float s0 = 0.f;
#pragma unroll
        for (int j = 0; j < 8; ++j) s0 += ftanh(A0[j] + hf8[j]) * vf8r[j];
        for (int off = 32; off; off >>= 1) s0 += __shfl_xor(s0, off);
        if (lane == 0) fsp[ii] = s0;
        float s1 = 0.f;
#pragma unroll
        for (int j = 0; j < 8; ++j) s1 += ftanh(A1[j] + hf8[j]) * vf8r[j];
        for (int off = 32; off; off >>= 1) s1 += __shfl_xor(s1, off);
        if (lane == 0) fsp[ii + 1] = s1;
        if (ii + 2 < 10) A0 = N0;
        if (ii + 3 < 10) A1 = N1;
      }
    }
    grid_barrier(bid, tid, ++ep);

    // ===== phase C: select + softmaxes + fvec + qvec (32 blocks) =====
    if (bid < 32) {
      const int b = bid;
      if (wave == 0) {
        float fsv[10];
        unsigned int keys[10];
#pragma unroll
        for (int c = 0; c < 10; ++c) {
          float v = fs_buf[b * CFL + c * 64 + lane];
          fsv[c] = v;
          sm.bc.fs_l[c * 64 + lane] = v;
          unsigned int u = __float_as_uint(v);
          keys[c] = (u & 0x80000000u) ? ~u : (u | 0x80000000u);
        }
        sm.bc.list_idx[lane] = lane;   // defensive prefill
        float lmax = fsv[0];
#pragma unroll
        for (int c = 1; c < 10; ++c) lmax = fmaxf(lmax, fsv[c]);
        for (int off = 32; off; off >>= 1) lmax = fmaxf(lmax, __shfl_xor(lmax, off));
        float maxv = lmax;

        unsigned int lo = 0u, hi = 0xFFFFFFFFu;
        for (int iter = 0; iter < 32; ++iter) {
          unsigned int span = hi - lo;
          unsigned int mid = lo + (span >> 1) + (span & 1u);
          int cnt = 0;
#pragma unroll
          for (int c = 0; c < 10; ++c) cnt += (keys[c] >= mid) ? 1 : 0;
          for (int off = 32; off; off >>= 1) cnt += __shfl_xor(cnt, off);
          if (cnt >= 64) lo = mid; else hi = mid - 1u;
        }
        unsigned int tau = lo;
        int cg_ = 0;
#pragma unroll
        for (int c = 0; c < 10; ++c) cg_ += (keys[c] > tau) ? 1 : 0;
        for (int off = 32; off; off >>= 1) cg_ += __shfl_xor(cg_, off);
        int cnt_gt = cg_;
        int ties_take = 64 - cnt_gt;
        if (ties_take < 0) ties_take = 0;

        int ngt = 0, neq = 0;
#pragma unroll
        for (int c = 0; c < 10; ++c) {
          unsigned int k = keys[c];
          unsigned long long mgt = __ballot(k > tau);
          unsigned long long meq = __ballot(k == tau);
          unsigned long long below = (1ull << lane) - 1ull;
          if (k > tau) {
            int pos = ngt + __popcll(mgt & below);
            if (pos < 64) sm.bc.list_idx[pos] = c * 64 + lane;
          } else if (k == tau) {
            int er = neq + __popcll(meq & below);
            int pos = cnt_gt + er;
            if (er < ties_take && pos < 64) sm.bc.list_idx[pos] = c * 64 + lane;
          }
          ngt += __popcll(mgt);
          neq += __popcll(meq);
        }
        float v = sm.bc.fs_l[sm.bc.list_idx[lane]];
        float e = __expf(v - maxv);
        float s = e;
        for (int off = 32; off; off >>= 1) s += __shfl_xor(s, off);
        sm.bc.list_w[lane] = e / s;
      } else {
        float hq8[8], vq8[8];
        const float* hp = hA + b * 3072 + lane * 8;
#pragma unroll
        for (int j = 0; j < 8; ++j) hq8[j] = hp[j];
        const float* vp = vq + lane * 8;
#pragma unroll
        for (int j = 0; j < 8; ++j) vq8[j] = vp[j];
        for (int s = wave - 1; s < 32; s += 7) {
          const float* qp = q_proj + (size_t)(b * CS + s) * 512 + lane * 8;
          float acc = 0.f;
#pragma unroll
          for (int j = 0; j < 8; ++j) acc += ftanh(qp[j] + hq8[j]) * vq8[j];
          for (int off = 32; off; off >>= 1) acc += __shfl_xor(acc, off);
          if (lane == 0) sm.bc.qs_l[s] = acc;
        }
      }
      __syncthreads();
      if (wave == 0 && lane < 32) {
        float v = sm.bc.qs_l[lane];
        float m = v;
        for (int off = 16; off; off >>= 1) m = fmaxf(m, __shfl_xor(m, off));
        float e = __expf(v - m);
        float s = e;
        for (int off = 16; off; off >>= 1) s += __shfl_xor(s, off);
        sm.bc.qw_l[lane] = e / s;
      }
      __syncthreads();

      const int d = tid;   // 0..511
      float f0 = 0.f;
      for (int j = 0; j < 64; ++j) {
        int idx = sm.bc.list_idx[j];
        float w = sm.bc.list_w[j];
        f0 += w * facts[((size_t)(b * CFL + idx)) * 512 + d];
      }
      const int row = t * CB + b;
      xq[b * 1024 + d] = f0;
      act_all[(size_t)row * 2560 + 1024 + d] = f0;

      float q0 = 0.f;
      for (int s = 0; s < 32; ++s) {
        q0 += sm.bc.qw_l[s] * bq[((size_t)(b * CS + s)) * 512 + d];
      }
      xq[b * 1024 + 512 + d] = q0;
      act_all[(size_t)row * 2560 + 1536 + d] = q0;
      act_all[(size_t)row * 2560 + 2048 + d] = q0;
    }
    grid_barrier(bid, tid, ++ep);

    // ===== phase D: gates GEMM (gate-permuted cols) + cell update; 64 blocks, 8-way K-split =====
    if (bid < 64) {
      const int n0 = bid * 32;        // permuted col space: unit = (n0+c)>>2, gate = (n0+c)&3
      const int kb = wave * 192;
      floatx4 acc[2][2];
#pragma unroll
      for (int mi = 0; mi < 2; ++mi)
#pragma unroll
        for (int ni = 0; ni < 2; ++ni) acc[mi][ni] = (floatx4){0.f, 0.f, 0.f, 0.f};
      const short* bhp = BTCh + (size_t)(n0 + l16) * 1536 + kb + quad * 8;
      const short* blp = BTCl + (size_t)(n0 + l16) * 1536 + kb + quad * 8;
#pragma unroll 1
      for (int s6 = 0; s6 < 6; ++s6) {
        int k0 = kb + s6 * 32;
        const float *a0p, *a1p;
        if (k0 < 1024) {
          a0p = xq + (size_t)l16 * 1024 + k0 + quad * 8;
          a1p = a0p + (size_t)16 * 1024;
        } else {
          a0p = act_all + (size_t)(t * CB + l16) * 2560 + 512 + (k0 - 1024) + quad * 8;
          a1p = a0p + (size_t)16 * 2560;
        }
        short8 a0h, a0l, a1h, a1l;
        split8(a0p, a0h, a0l);
        split8(a1p, a1h, a1l);
#pragma unroll
        for (int ni = 0; ni < 2; ++ni) {
          short8 bh = *(const short8*)(bhp + (size_t)(ni * 16) * 1536 + s6 * 32);
          short8 bl = *(const short8*)(blp + (size_t)(ni * 16) * 1536 + s6 * 32);
          acc[0][ni] = __builtin_amdgcn_mfma_f32_16x16x32_bf16(a0h, bh, acc[0][ni], 0, 0, 0);
          acc[0][ni] = __builtin_amdgcn_mfma_f32_16x16x32_bf16(a0l, bh, acc[0][ni], 0, 0, 0);
          acc[0][ni] = __builtin_amdgcn_mfma_f32_16x16x32_bf16(a0h, bl, acc[0][ni], 0, 0, 0);
          acc[1][ni] = __builtin_amdgcn_mfma_f32_16x16x32_bf16(a1h, bh, acc[1][ni], 0, 0, 0);
          acc[1][ni] = __builtin_amdgcn_mfma_f32_16x16x32_bf16(a1l, bh, acc[1][ni], 0, 0, 0);
          acc[1][ni] = __builtin_amdgcn_mfma_f32_16x16x32_bf16(a1h, bl, acc[1][ni], 0, 0, 0);
        }
      }
#pragma unroll
      for (int mi = 0; mi < 2; ++mi)
#pragma unroll
        for (int ni = 0; ni < 2; ++ni) {
#pragma unroll
          for (int r = 0; r < 4; ++r)
            sm.zsum[wave][mi * 16 + quad * 4 + r][ni * 16 + l16] = acc[mi][ni][r];
        }
      __syncthreads();

      if (tid < 256) {
        int bb = tid >> 3, ul = tid & 7;
        int u = (n0 >> 2) + ul;
        float z[4];
#pragma unroll
        for (int g = 0; g < 4; ++g) {
          int c = ul * 4 + g;
          float s = 0.f;
#pragma unroll
          for (int w = 0; w < 8; ++w) s += sm.zsum[w][bb][c];
          z[g] = s + hA[(size_t)bb * 3072 + 1024 + n0 + c] + lstm_b[g * 512 + u];
        }
        int ci = bb * 512 + u;
        float cold = c_buf[ci];
        float c2 = sigf(z[1]) * cold + sigf(z[0]) * ftanh(z[2]);
        float h2 = sigf(z[3]) * ftanh(c2);
        c_buf[ci] = c2;
        h_buf[ci] = h2;
        act_all[(size_t)(t * CB + bb) * 2560 + u] = h2;
      }
    }
    grid_barrier(bid, tid, ++ep);
  }
}

// ---------------- maxout (+ biases) ----------------
__global__ void maxout_kernel(const float* __restrict__ R, const float* __restrict__ br,
                              const float* __restrict__ bur, const float* __restrict__ bvr,
                              short* __restrict__ m_buf) {
  int idx = blockIdx.x * 256 + threadIdx.x;  // < 768*512
  int r = idx >> 9, j = idx & 511;
  int n0 = j * 2, n1 = j * 2 + 1;
  float v0 = R[(size_t)r * 1024 + n0] + br[n0] + bur[n0] + bvr[n0];
  float v1 = R[(size_t)r * 1024 + n1] + br[n1] + bur[n1] + bvr[n1];
  m_buf[(size_t)r * 512 + j] = f2bf(fmaxf(v0, v1));
}

// ---------------- logits GEMM: bf16 A,B -> f32 out + f32 bias ----------------
__global__ __launch_bounds__(256) void gemm_bf_kernel(
    const short* __restrict__ A, const short* __restrict__ BT,
    float* __restrict__ C, const float* __restrict__ bias, int N, int K) {
  const int lane = threadIdx.x & 63;
  const int wave = threadIdx.x >> 6;
  const int quad = lane >> 4;
  const int l16 = lane & 15;
  const int m_base = blockIdx.x * 64 + (wave & 1) * 32;
  const int n_base = blockIdx.y * 128 + (wave >> 1) * 64;

  floatx4 acc[2][4];
#pragma unroll
  for (int mi = 0; mi < 2; ++mi)
#pragma unroll
    for (int ni = 0; ni < 4; ++ni) acc[mi][ni] = (floatx4){0.f, 0.f, 0.f, 0.f};

  const short* a0p = A + (size_t)(m_base + l16) * K + quad * 8;
  const short* a1p = a0p + (size_t)16 * K;
  const short* b0p = BT + (size_t)(n_base + l16) * K + quad * 8;

  for (int k0 = 0; k0 < K; k0 += 32) {
    short8 a0 = *(const short8*)(a0p + k0);
    short8 a1 = *(const short8*)(a1p + k0);
#pragma unroll
    for (int ni = 0; ni < 4; ++ni) {
      short8 bb = *(const short8*)(b0p + (size_t)(ni * 16) * K + k0);
      acc[0][ni] = __builtin_amdgcn_mfma_f32_16x16x32_bf16(a0, bb, acc[0][ni], 0, 0, 0);
      acc[1][ni] = __builtin_amdgcn_mfma_f32_16x16x32_bf16(a1, bb, acc[1][ni], 0, 0, 0);
    }
  }
#pragma unroll
  for (int mi = 0; mi < 2; ++mi)
#pragma unroll
    for (int ni = 0; ni < 4; ++ni) {
      int col = n_base + ni * 16 + l16;
#pragma unroll
      for (int r = 0; r < 4; ++r) {
        int row = m_base + mi * 16 + quad * 4 + r;
        C[(size_t)row * N + col] = acc[mi][ni][r] + bias[col];
      }
    }
}

// ---------------- launch ----------------
extern "C" void kernel_launch(void* const* d_in, const int* in_sizes, int n_in,
                              void* d_out, int out_size, void* d_ws, size_t ws_size,
                              hipStream_t stream) {
  const float* bq     = (const float*)d_in[0];
  const float* facts  = (const float*)d_in[1];
  const int*   target = (const int*)d_in[2];
  const float* emb    = (const float*)d_in[4];
  const float* lstm_k = (const float*)d_in[5];
  const float* lstm_r = (const float*)d_in[6];
  const float* lstm_b = (const float*)d_in[7];
  const float* Wq1 = (const float*)d_in[8];
  const float* Wq2 = (const float*)d_in[9];
  const float* vq  = (const float*)d_in[10];
  const float* Wf1 = (const float*)d_in[11];
  const float* Wf2 = (const float*)d_in[12];
  const float* vf  = (const float*)d_in[13];
  const float* Wr  = (const float*)d_in[14];
  const float* br  = (const float*)d_in[15];
  const float* Ur  = (const float*)d_in[16];
  const float* bur = (const float*)d_in[17];
  const float* Vr  = (const float*)d_in[18];
  const float* bvr = (const float*)d_in[19];
  const float* Wy  = (const float*)d_in[20];
  const float* by  = (const float*)d_in[21];

  char* ws = (char*)d_ws;
  float* f_proj  = (float*)(ws + OFF_FPROJ);
  float* q_proj  = (float*)(ws + OFF_QPROJ);
  short* BTAh    = (short*)(ws + OFF_BTA);
  short* BTAl    = BTAh + (size_t)3072 * 512;
  short* BTCh    = (short*)(ws + OFF_BTC);
  short* BTCl    = BTCh + (size_t)2048 * 1536;
  float* act_all = (float*)(ws + OFF_ACT);
  short* BTW1h   = (short*)(ws + OFF_ACT);            // setup-phase alias (dies before gather_prev)
  short* BTW1l   = BTW1h + (size_t)512 * 512;
  float* hA      = (float*)(ws + OFF_HA);
  float* h_buf   = (float*)(ws + OFF_H);
  float* xq      = (float*)(ws + OFF_XQ);
  float* c_buf   = (float*)(ws + OFF_C);
  float* fs_buf  = (float*)(ws + OFF_FS);
  short* BTY     = (short*)(ws + OFF_BTY);
  short* BTRh    = (short*)(ws + OFF_BTR);
  short* BTRl    = BTRh + (size_t)1024 * 2560;
  float* R_buf   = (float*)(ws + OFF_RBUF);
  short* m_buf   = (short*)(ws + OFF_MBUF);
  float* out     = (float*)d_out;

  auto TS = [&](const float* src, int sld, int srow0, short* dh, short* dl, int dld,
                int drow0, int dcol0, int NR, int NK, int perm) {
    transpose_split_kernel<<<dim3(NR / 64, NK / 64), 256, 0, stream>>>(
        src, sld, srow0, dh, dl, dld, drow0, dcol0, perm);
  };

  // --- persistent transposed + pre-split weights (bf16 hi/lo) ---
  TS(Wq2, 512, 0, BTAh, BTAl, 512, 0, 0, 512, 512, 0);
  TS(Wf2, 512, 0, BTAh, BTAl, 512, 512, 0, 512, 512, 0);
  TS(lstm_r, 2048, 0, BTAh, BTAl, 512, 1024, 0, 2048, 512, 1);         // gate-permuted
  TS(lstm_k, 2048, 512, BTCh, BTCl, 1536, 0, 0, 2048, 512, 1);         // fvec K-part, permuted
  TS(lstm_k, 2048, 1024, BTCh, BTCl, 1536, 0, 512, 2048, 512, 1);      // qvec K-part, permuted
  TS(lstm_k, 2048, 0, BTCh, BTCl, 1536, 0, 1024, 2048, 512, 1);        // prev K-part, permuted

  // --- hoisted projections (BTW1 aliases act_all; used before gather_prev) ---
  TS(Wq1, 512, 0, BTW1h, BTW1l, 512, 0, 0, 512, 512, 0);
  gemm_bsw_kernel<<<dim3(32, 1), 256, 0, stream>>>(bq, BTW1h, BTW1l, q_proj, 512, 512);
  TS(Wf1, 512, 0, BTW1h, BTW1l, 512, 0, 0, 512, 512, 0);
  gemm_bsw_kernel<<<dim3(640, 1), 256, 0, stream>>>(facts, BTW1h, BTW1l, f_proj, 512, 512);

  // --- init recurrent state + barrier cells + prev tokens ---
  init_kernel<<<64, 256, 0, stream>>>(h_buf, c_buf);
  gather_prev_kernel<<<768, 256, 0, stream>>>(target, emb, act_all);

  // --- recurrence: persistent kernel, full grid, 4 flag-barriers per step ---
  recurrence_kernel<<<NBLK, 512, 0, stream>>>(f_proj, q_proj, BTAh, BTAl, BTCh, BTCl,
                                              facts, bq, vq, vf, lstm_b,
                                              hA, h_buf, c_buf, xq, fs_buf, act_all);

  // --- end-stage weights into dead regions ---
  TS(Wr, 1024, 0, BTRh, BTRl, 2560, 0, 0, 1024, 512, 0);
  TS(Ur, 1024, 0, BTRh, BTRl, 2560, 0, 512, 1024, 1536, 0);
  TS(Vr, 1024, 0, BTRh, BTRl, 2560, 0, 2048, 1024, 512, 0);
  transpose_f2b_kernel<<<dim3(500, 8), 256, 0, stream>>>(Wy, 32000, BTY, 512);

  // --- batched readout + maxout + logits ---
  gemm_bsw_kernel<<<dim3(24, 2), 256, 0, stream>>>(act_all, BTRh, BTRl, R_buf, 1024, 2560);
  maxout_kernel<<<1536, 256, 0, stream>>>(R_buf, br, bur, bvr, m_buf);
  gemm_bf_kernel<<<dim3(12, 250), 256, 0, stream>>>(m_buf, BTY, out, by, 32000, 512);
}

// Round 5
// 2855.386 us; speedup vs baseline: 3.0218x; 2.9447x over previous
//
#include <hip/hip_runtime.h>
#include <cstdint>
#include <cstddef>

// ---------------- constants ----------------
constexpr int CB = 32;      // batch
constexpr int CS = 32;      // question seq
constexpr int CFL = 640;    // F*L
constexpr int CT = 24;      // steps
constexpr int NBLK = 256;   // persistent grid size

typedef __attribute__((ext_vector_type(8))) short short8;
typedef __attribute__((ext_vector_type(4))) float floatx4;
typedef __attribute__((ext_vector_type(8))) float float8;

// ---------------- helpers ----------------
__device__ __forceinline__ float bf2f(short s) {
  return __uint_as_float(((unsigned int)(unsigned short)s) << 16);
}
__device__ __forceinline__ short f2bf(float f) {
  unsigned int u = __float_as_uint(f);
  u = (u + 0x7FFFu + ((u >> 16) & 1u)) >> 16;
  return (short)u;
}
// exact split: f = hi + lo + O(2^-18 |f|)
__device__ __forceinline__ void split8(const float* __restrict__ p, short8& hi, short8& lo) {
#pragma unroll
  for (int j = 0; j < 8; ++j) {
    float f = p[j];
    short h = f2bf(f);
    hi[j] = h;
    lo[j] = f2bf(f - bf2f(h));
  }
}
__device__ __forceinline__ float sigf(float x) { return 1.f / (1.f + __expf(-x)); }
__device__ __forceinline__ float ftanh(float x) {
  float e = __expf(2.f * x);
  return 1.f - 2.f / (e + 1.f);
}

// ---- coherent (agent-scope, relaxed) data access: sc1 load/store, NO fences ----
__device__ __forceinline__ void st_sys(float* p, float v) {
  __hip_atomic_store((unsigned int*)p, __float_as_uint(v),
                     __ATOMIC_RELAXED, __HIP_MEMORY_SCOPE_AGENT);
}
__device__ __forceinline__ float ld_sys(const float* p) {
  unsigned int u = __hip_atomic_load((const unsigned int*)p,
                                     __ATOMIC_RELAXED, __HIP_MEMORY_SCOPE_AGENT);
  return __uint_as_float(u);
}

// ---------------- ws layout (bytes), total 71,516,160 B = 68.2 MiB ----------------
constexpr size_t OFF_FPROJ = 0;            // [20480][512] f32 = 41,943,040
constexpr size_t OFF_QPROJ = 41943040;     // [1024][512]  f32 =  2,097,152
constexpr size_t OFF_BTA   = 44040192;     // BTAh+BTAl [3072][512] bf16 pair = 6,291,456
constexpr size_t OFF_BTC   = 50331648;     // BTCh+BTCl [2048][1536] bf16 pair = 12,582,912
constexpr size_t OFF_ACT   = 62914560;     // [768][2560]  f32 = 7,864,320 (setup-alias: BTW1h/l bf16)
constexpr size_t OFF_HA    = 70778880;     // [32][3072]   f32 =    393,216
constexpr size_t OFF_H     = 71172096;     // [32][512]    f32 =     65,536
constexpr size_t OFF_XQ    = 71237632;     // [32][1024]   f32 =    131,072
constexpr size_t OFF_C     = 71368704;     // [32][512]    f32 =     65,536
constexpr size_t OFF_FS    = 71434240;     // [32][640]    f32 =     81,920 -> 71,516,160
// phase-2 (after recurrence; FPROJ/QPROJ/BTC dead):
constexpr size_t OFF_BTY   = 0;            // [32000][512] bf16 = 32,768,000
constexpr size_t OFF_BTR   = 32768000;     // BTRh+BTRl [1024][2560] bf16 pair = 10,485,760
constexpr size_t OFF_RBUF  = OFF_BTC;      // [768][1024]  f32  =  3,145,728
constexpr size_t OFF_MBUF  = OFF_BTC + 3145728;  // [768][512] bf16 = 786,432

// ---------------- fence-free grid barrier (relaxed atomics only) ----------------
__device__ unsigned g_arrive[NBLK * 16];   // 64B stride per block
__device__ unsigned g_epoch;

__device__ __forceinline__ void grid_barrier(int bid, int tid, unsigned ep) {
  // Every wave drains its own VMEM (sc1 stores are then visible at the IC).
  asm volatile("s_waitcnt vmcnt(0) lgkmcnt(0)" ::: "memory");
  __syncthreads();
  if (tid == 0)
    __hip_atomic_store(&g_arrive[bid * 16], ep, __ATOMIC_RELAXED, __HIP_MEMORY_SCOPE_AGENT);
  if (bid == 0) {
    if (tid < NBLK) {
      while (__hip_atomic_load(&g_arrive[tid * 16], __ATOMIC_RELAXED, __HIP_MEMORY_SCOPE_AGENT) < ep) {
      }
    }
    __syncthreads();
    if (tid == 0)
      __hip_atomic_store(&g_epoch, ep, __ATOMIC_RELAXED, __HIP_MEMORY_SCOPE_AGENT);
  }
  if (tid == 0) {
    while (__hip_atomic_load(&g_epoch, __ATOMIC_RELAXED, __HIP_MEMORY_SCOPE_AGENT) < ep) {
      __builtin_amdgcn_s_sleep(1);
    }
  }
  __syncthreads();
}

// ---------------- init: zero h, c and barrier cells ----------------
__global__ void init_kernel(float* h, float* c_buf) {
  int i = blockIdx.x * 256 + threadIdx.x;
  if (i < 16384) { h[i] = 0.f; c_buf[i] = 0.f; }
  if (i < NBLK * 16) g_arrive[i] = 0u;
  if (i == 0) g_epoch = 0u;
}

// ---------------- gather prev tokens into act_all cols [512,1024) ----------------
__global__ void gather_prev_kernel(const int* __restrict__ target, const float* __restrict__ emb,
                                   float* __restrict__ act_all) {
  int r = blockIdx.x;            // 0..767 = t*32+b
  int t = r >> 5, b = r & 31;
  int tok = (t == 0) ? -1 : target[b * CT + (t - 1)];
  for (int e = threadIdx.x; e < 512; e += 256) {
    float v = (tok < 0) ? 0.f : emb[(size_t)tok * 512 + e];
    act_all[(size_t)r * 2560 + 512 + e] = v;
  }
}

// ---------------- fp32 transpose + hi/lo bf16 pre-split (optional gate-permute of rows) ----------------
__global__ __launch_bounds__(256) void transpose_split_kernel(
    const float* __restrict__ src, int src_ld, int src_row0,
    short* __restrict__ dsth, short* __restrict__ dstl,
    int dst_ld, int dst_row0, int dst_col0, int perm) {
  __shared__ float tile[64][65];
  int n0 = blockIdx.x * 64, k0 = blockIdx.y * 64;
  for (int it = 0; it < 16; ++it) {
    int idx = threadIdx.x + it * 256;
    int kk = idx >> 6, nn = idx & 63;
    tile[kk][nn] = src[(size_t)(src_row0 + k0 + kk) * src_ld + n0 + nn];
  }
  __syncthreads();
  for (int it = 0; it < 16; ++it) {
    int idx = threadIdx.x + it * 256;
    int nn = idx >> 6, kk = idx & 63;
    float f = tile[kk][nn];
    short hv = f2bf(f);
    int r = n0 + nn;
    int pr = perm ? (((r & 511) << 2) | (r >> 9)) : r;   // gate-major -> unit-major*4+gate
    size_t o = (size_t)(dst_row0 + pr) * dst_ld + dst_col0 + k0 + kk;
    dsth[o] = hv;
    dstl[o] = f2bf(f - bf2f(hv));
  }
}

// ---------------- fp32 -> bf16 transpose (for Wy) ----------------
__global__ __launch_bounds__(256) void transpose_f2b_kernel(
    const float* __restrict__ src, int src_ld,
    short* __restrict__ dst, int dst_ld) {
  __shared__ float tile[64][65];
  int n0 = blockIdx.x * 64, k0 = blockIdx.y * 64;
  for (int it = 0; it < 16; ++it) {
    int idx = threadIdx.x + it * 256;
    int kk = idx >> 6, nn = idx & 63;
    tile[kk][nn] = src[(size_t)(k0 + kk) * src_ld + n0 + nn];
  }
  __syncthreads();
  for (int it = 0; it < 16; ++it) {
    int idx = threadIdx.x + it * 256;
    int nn = idx >> 6, kk = idx & 63;
    dst[(size_t)(n0 + nn) * dst_ld + k0 + kk] = f2bf(tile[kk][nn]);
  }
}

// ---------------- wide split GEMM, pre-split B: C[M,N] = A[M,K]f32 @ (BTh+BTl)[N,K]^T ----------------
__global__ __launch_bounds__(256) void gemm_bsw_kernel(
    const float* __restrict__ A, const short* __restrict__ BTh, const short* __restrict__ BTl,
    float* __restrict__ C, int N, int K) {
  const int lane = threadIdx.x & 63;
  const int wave = threadIdx.x >> 6;
  const int quad = lane >> 4;
  const int l16 = lane & 15;
  const int m_base = blockIdx.x * 32;
  const int n_base = blockIdx.y * 512 + wave * 128;

  floatx4 acc[2][8];
#pragma unroll
  for (int mi = 0; mi < 2; ++mi)
#pragma unroll
    for (int ni = 0; ni < 8; ++ni) acc[mi][ni] = (floatx4){0.f, 0.f, 0.f, 0.f};

  const float* a0p = A + (size_t)(m_base + l16) * K + quad * 8;
  const float* a1p = a0p + (size_t)16 * K;
  const short* bhp = BTh + (size_t)(n_base + l16) * K + quad * 8;
  const short* blp = BTl + (size_t)(n_base + l16) * K + quad * 8;

  for (int k0 = 0; k0 < K; k0 += 32) {
    short8 a0h, a0l, a1h, a1l;
    split8(a0p + k0, a0h, a0l);
    split8(a1p + k0, a1h, a1l);
#pragma unroll
    for (int ni = 0; ni < 8; ++ni) {
      short8 bh = *(const short8*)(bhp + (size_t)(ni * 16) * K + k0);
      short8 bl = *(const short8*)(blp + (size_t)(ni * 16) * K + k0);
      acc[0][ni] = __builtin_amdgcn_mfma_f32_16x16x32_bf16(a0h, bh, acc[0][ni], 0, 0, 0);
      acc[0][ni] = __builtin_amdgcn_mfma_f32_16x16x32_bf16(a0l, bh, acc[0][ni], 0, 0, 0);
      acc[0][ni] = __builtin_amdgcn_mfma_f32_16x16x32_bf16(a0h, bl, acc[0][ni], 0, 0, 0);
      acc[1][ni] = __builtin_amdgcn_mfma_f32_16x16x32_bf16(a1h, bh, acc[1][ni], 0, 0, 0);
      acc[1][ni] = __builtin_amdgcn_mfma_f32_16x16x32_bf16(a1l, bh, acc[1][ni], 0, 0, 0);
      acc[1][ni] = __builtin_amdgcn_mfma_f32_16x16x32_bf16(a1h, bl, acc[1][ni], 0, 0, 0);
    }
  }
#pragma unroll
  for (int mi = 0; mi < 2; ++mi)
#pragma unroll
    for (int ni = 0; ni < 8; ++ni) {
      int col = n_base + ni * 16 + l16;
#pragma unroll
      for (int r = 0; r < 4; ++r) {
        int row = m_base + mi * 16 + quad * 4 + r;
        C[(size_t)row * N + col] = acc[mi][ni][r];
      }
    }
}

// ---------------- shared memory for the persistent kernel ----------------
struct SharedBC {
  float fs_l[640];
  int   list_idx[64];
  float list_w[64];
  float qs_l[32];
  float qw_l[32];
};
union SharedU {
  float zsum[8][32][33];   // phases A and D; [33] pad -> conflict-free partial-sum stores
  SharedBC bc;             // phase C
};

// ---------------- persistent recurrence kernel: 256 blocks x 512 threads ----------------
__global__ __launch_bounds__(512, 2) void recurrence_kernel(
    const float* __restrict__ f_proj, const float* __restrict__ q_proj,
    const short* __restrict__ BTAh, const short* __restrict__ BTAl,
    const short* __restrict__ BTCh, const short* __restrict__ BTCl,
    const float* __restrict__ facts, const float* __restrict__ bq,
    const float* __restrict__ vq, const float* __restrict__ vf,
    const float* __restrict__ lstm_b,
    float* __restrict__ hA, float* __restrict__ h_buf, float* __restrict__ c_buf,
    float* __restrict__ xq, float* __restrict__ fs_buf, float* __restrict__ act_all) {
  __shared__ SharedU sm;
  const int bid = blockIdx.x;
  const int tid = threadIdx.x;
  const int lane = tid & 63;
  const int wave = tid >> 6;     // 0..7
  const int quad = lane >> 4;
  const int l16 = lane & 15;
  unsigned ep = 0;

#pragma unroll 1
  for (int t = 0; t < CT; ++t) {
    // ===== phase A: hA[32,3072] = h @ BTA^T; 96 blocks, 8-way K-split =====
    if (bid < 96) {
      const int n0 = bid * 32;
      const int kb = wave * 64;
      floatx4 acc[2][2];
#pragma unroll
      for (int mi = 0; mi < 2; ++mi)
#pragma unroll
        for (int ni = 0; ni < 2; ++ni) acc[mi][ni] = (floatx4){0.f, 0.f, 0.f, 0.f};
      const float* a0p = h_buf + (size_t)l16 * 512 + kb + quad * 8;
      const float* a1p = a0p + (size_t)16 * 512;
      const short* bhp = BTAh + (size_t)(n0 + l16) * 512 + kb + quad * 8;
      const short* blp = BTAl + (size_t)(n0 + l16) * 512 + kb + quad * 8;
#pragma unroll
      for (int k0 = 0; k0 < 64; k0 += 32) {
        float t0[8], t1[8];
#pragma unroll
        for (int j = 0; j < 8; ++j) { t0[j] = ld_sys(a0p + k0 + j); t1[j] = ld_sys(a1p + k0 + j); }
        short8 a0h, a0l, a1h, a1l;
        split8(t0, a0h, a0l);
        split8(t1, a1h, a1l);
#pragma unroll
        for (int ni = 0; ni < 2; ++ni) {
          short8 bh = *(const short8*)(bhp + (size_t)(ni * 16) * 512 + k0);
          short8 bl = *(const short8*)(blp + (size_t)(ni * 16) * 512 + k0);
          acc[0][ni] = __builtin_amdgcn_mfma_f32_16x16x32_bf16(a0h, bh, acc[0][ni], 0, 0, 0);
          acc[0][ni] = __builtin_amdgcn_mfma_f32_16x16x32_bf16(a0l, bh, acc[0][ni], 0, 0, 0);
          acc[0][ni] = __builtin_amdgcn_mfma_f32_16x16x32_bf16(a0h, bl, acc[0][ni], 0, 0, 0);
          acc[1][ni] = __builtin_amdgcn_mfma_f32_16x16x32_bf16(a1h, bh, acc[1][ni], 0, 0, 0);
          acc[1][ni] = __builtin_amdgcn_mfma_f32_16x16x32_bf16(a1l, bh, acc[1][ni], 0, 0, 0);
          acc[1][ni] = __builtin_amdgcn_mfma_f32_16x16x32_bf16(a1h, bl, acc[1][ni], 0, 0, 0);
        }
      }
#pragma unroll
      for (int mi = 0; mi < 2; ++mi)
#pragma unroll
        for (int ni = 0; ni < 2; ++ni) {
#pragma unroll
          for (int r = 0; r < 4; ++r)
            sm.zsum[wave][mi * 16 + quad * 4 + r][ni * 16 + l16] = acc[mi][ni][r];
        }
      __syncthreads();
      for (int o = tid; o < 1024; o += 512) {
        int bb = o >> 5, c = o & 31;
        float s = 0.f;
#pragma unroll
        for (int w = 0; w < 8; ++w) s += sm.zsum[w][bb][c];
        st_sys(&hA[(size_t)bb * 3072 + n0 + c], s);
      }
    }
    grid_barrier(bid, tid, ++ep);

    // ===== phase B: fact scores on all 256 blocks (80 rows/block, 10 rows/wave) =====
    {
      const int b = bid >> 3;
      const int row0 = (bid & 7) * 80 + wave * 10;
      float hf8[8], vf8r[8];
      const float* hp = hA + b * 3072 + 512 + lane * 8;
#pragma unroll
      for (int j = 0; j < 8; ++j) hf8[j] = ld_sys(hp + j);
      const float* vp = vf + lane * 8;
#pragma unroll
      for (int j = 0; j < 8; ++j) vf8r[j] = vp[j];
      const float* base = f_proj + ((size_t)(b * CFL + row0)) * 512 + lane * 8;
      float* fsp = fs_buf + b * CFL + row0;

      float8 A0 = *(const float8*)(base);
      float8 A1 = *(const float8*)(base + 512);
#pragma unroll
      for (int ii = 0; ii < 10; ii += 2) {
        float8 N0, N1;
        if (ii + 2 < 10) N0 = *(const float8*)(base + (size_t)(ii + 2) * 512);
        if (ii + 3 < 10) N1 = *(const float8*)(base + (size_t)(ii + 3) * 512);
        float s0 = 0.f;
#pragma unroll
        for (int j = 0; j < 8; ++j) s0 += ftanh(A0[j] + hf8[j]) * vf8r[j];
        for (int off = 32; off; off >>= 1) s0 += __shfl_xor(s0, off);
        if (lane == 0) st_sys(&fsp[ii], s0);
        float s1 = 0.f;
#pragma unroll
        for (int j = 0; j < 8; ++j) s1 += ftanh(A1[j] + hf8[j]) * vf8r[j];
        for (int off = 32; off; off >>= 1) s1 += __shfl_xor(s1, off);
        if (lane == 0) st_sys(&fsp[ii + 1], s1);
        if (ii + 2 < 10) A0 = N0;
        if (ii + 3 < 10) A1 = N1;
      }
    }
    grid_barrier(bid, tid, ++ep);

    // ===== phase C: select + softmaxes + fvec + qvec (32 blocks) =====
    if (bid < 32) {
      const int b = bid;
      if (wave == 0) {
        float fsv[10];
        unsigned int keys[10];
#pragma unroll
        for (int c = 0; c < 10; ++c) {
          float v = ld_sys(&fs_buf[b * CFL + c * 64 + lane]);
          fsv[c] = v;
          sm.bc.fs_l[c * 64 + lane] = v;
          unsigned int u = __float_as_uint(v);
          keys[c] = (u & 0x80000000u) ? ~u : (u | 0x80000000u);
        }
        sm.bc.list_idx[lane] = lane;   // defensive prefill
        float lmax = fsv[0];
#pragma unroll
        for (int c = 1; c < 10; ++c) lmax = fmaxf(lmax, fsv[c]);
        for (int off = 32; off; off >>= 1) lmax = fmaxf(lmax, __shfl_xor(lmax, off));
        float maxv = lmax;

        unsigned int lo = 0u, hi = 0xFFFFFFFFu;
        for (int iter = 0; iter < 32; ++iter) {
          unsigned int span = hi - lo;
          unsigned int mid = lo + (span >> 1) + (span & 1u);
          int cnt = 0;
#pragma unroll
          for (int c = 0; c < 10; ++c) cnt += (keys[c] >= mid) ? 1 : 0;
          for (int off = 32; off; off >>= 1) cnt += __shfl_xor(cnt, off);
          if (cnt >= 64) lo = mid; else hi = mid - 1u;
        }
        unsigned int tau = lo;
        int cg_ = 0;
#pragma unroll
        for (int c = 0; c < 10; ++c) cg_ += (keys[c] > tau) ? 1 : 0;
        for (int off = 32; off; off >>= 1) cg_ += __shfl_xor(cg_, off);
        int cnt_gt = cg_;
        int ties_take = 64 - cnt_gt;
        if (ties_take < 0) ties_take = 0;

        int ngt = 0, neq = 0;
#pragma unroll
        for (int c = 0; c < 10; ++c) {
          unsigned int k = keys[c];
          unsigned long long mgt = __ballot(k > tau);
          unsigned long long meq = __ballot(k == tau);
          unsigned long long below = (1ull << lane) - 1ull;
          if (k > tau) {
            int pos = ngt + __popcll(mgt & below);
            if (pos < 64) sm.bc.list_idx[pos] = c * 64 + lane;
          } else if (k == tau) {
            int er = neq + __popcll(meq & below);
            int pos = cnt_gt + er;
            if (er < ties_take && pos < 64) sm.bc.list_idx[pos] = c * 64 + lane;
          }
          ngt += __popcll(mgt);
          neq += __popcll(meq);
        }
        float v = sm.bc.fs_l[sm.bc.list_idx[lane]];
        float e = __expf(v - maxv);
        float s = e;
        for (int off = 32; off; off >>= 1) s += __shfl_xor(s, off);
        sm.bc.list_w[lane] = e / s;
      } else {
        float hq8[8], vq8[8];
        const float* hp = hA + b * 3072 + lane * 8;
#pragma unroll
        for (int j = 0; j < 8; ++j) hq8[j] = ld_sys(hp + j);
        const float* vp = vq + lane * 8;
#pragma unroll
        for (int j = 0; j < 8; ++j) vq8[j] = vp[j];
        for (int s = wave - 1; s < 32; s += 7) {
          const float* qp = q_proj + (size_t)(b * CS + s) * 512 + lane * 8;
          float acc = 0.f;
#pragma unroll
          for (int j = 0; j < 8; ++j) acc += ftanh(qp[j] + hq8[j]) * vq8[j];
          for (int off = 32; off; off >>= 1) acc += __shfl_xor(acc, off);
          if (lane == 0) sm.bc.qs_l[s] = acc;
        }
      }
      __syncthreads();
      if (wave == 0 && lane < 32) {
        float v = sm.bc.qs_l[lane];
        float m = v;
        for (int off = 16; off; off >>= 1) m = fmaxf(m, __shfl_xor(m, off));
        float e = __expf(v - m);
        float s = e;
        for (int off = 16; off; off >>= 1) s += __shfl_xor(s, off);
        sm.bc.qw_l[lane] = e / s;
      }
      __syncthreads();

      const int d = tid;   // 0..511
      float f0 = 0.f;
      for (int j = 0; j < 64; ++j) {
        int idx = sm.bc.list_idx[j];
        float w = sm.bc.list_w[j];
        f0 += w * facts[((size_t)(b * CFL + idx)) * 512 + d];
      }
      const int row = t * CB + b;
      st_sys(&xq[b * 1024 + d], f0);
      act_all[(size_t)row * 2560 + 1024 + d] = f0;

      float q0 = 0.f;
      for (int s = 0; s < 32; ++s) {
        q0 += sm.bc.qw_l[s] * bq[((size_t)(b * CS + s)) * 512 + d];
      }
      st_sys(&xq[b * 1024 + 512 + d], q0);
      act_all[(size_t)row * 2560 + 1536 + d] = q0;
      act_all[(size_t)row * 2560 + 2048 + d] = q0;
    }
    grid_barrier(bid, tid, ++ep);

    // ===== phase D: gates GEMM (gate-permuted cols) + cell update; 64 blocks, 8-way K-split =====
    if (bid < 64) {
      const int n0 = bid * 32;        // permuted col space: unit = (n0+c)>>2, gate = (n0+c)&3
      const int kb = wave * 192;
      floatx4 acc[2][2];
#pragma unroll
      for (int mi = 0; mi < 2; ++mi)
#pragma unroll
        for (int ni = 0; ni < 2; ++ni) acc[mi][ni] = (floatx4){0.f, 0.f, 0.f, 0.f};
      const short* bhp = BTCh + (size_t)(n0 + l16) * 1536 + kb + quad * 8;
      const short* blp = BTCl + (size_t)(n0 + l16) * 1536 + kb + quad * 8;
#pragma unroll 1
      for (int s6 = 0; s6 < 6; ++s6) {
        int k0 = kb + s6 * 32;
        short8 a0h, a0l, a1h, a1l;
        if (k0 < 1024) {
          const float* a0p = xq + (size_t)l16 * 1024 + k0 + quad * 8;
          const float* a1p = a0p + (size_t)16 * 1024;
          float t0[8], t1[8];
#pragma unroll
          for (int j = 0; j < 8; ++j) { t0[j] = ld_sys(a0p + j); t1[j] = ld_sys(a1p + j); }
          split8(t0, a0h, a0l);
          split8(t1, a1h, a1l);
        } else {
          const float* a0p = act_all + (size_t)(t * CB + l16) * 2560 + 512 + (k0 - 1024) + quad * 8;
          const float* a1p = a0p + (size_t)16 * 2560;
          split8(a0p, a0h, a0l);
          split8(a1p, a1h, a1l);
        }
#pragma unroll
        for (int ni = 0; ni < 2; ++ni) {
          short8 bh = *(const short8*)(bhp + (size_t)(ni * 16) * 1536 + s6 * 32);
          short8 bl = *(const short8*)(blp + (size_t)(ni * 16) * 1536 + s6 * 32);
          acc[0][ni] = __builtin_amdgcn_mfma_f32_16x16x32_bf16(a0h, bh, acc[0][ni], 0, 0, 0);
          acc[0][ni] = __builtin_amdgcn_mfma_f32_16x16x32_bf16(a0l, bh, acc[0][ni], 0, 0, 0);
          acc[0][ni] = __builtin_amdgcn_mfma_f32_16x16x32_bf16(a0h, bl, acc[0][ni], 0, 0, 0);
          acc[1][ni] = __builtin_amdgcn_mfma_f32_16x16x32_bf16(a1h, bh, acc[1][ni], 0, 0, 0);
          acc[1][ni] = __builtin_amdgcn_mfma_f32_16x16x32_bf16(a1l, bh, acc[1][ni], 0, 0, 0);
          acc[1][ni] = __builtin_amdgcn_mfma_f32_16x16x32_bf16(a1h, bl, acc[1][ni], 0, 0, 0);
        }
      }
#pragma unroll
      for (int mi = 0; mi < 2; ++mi)
#pragma unroll
        for (int ni = 0; ni < 2; ++ni) {
#pragma unroll
          for (int r = 0; r < 4; ++r)
            sm.zsum[wave][mi * 16 + quad * 4 + r][ni * 16 + l16] = acc[mi][ni][r];
        }
      __syncthreads();

      if (tid < 256) {
        int bb = tid >> 3, ul = tid & 7;
        int u = (n0 >> 2) + ul;
        float z[4];
#pragma unroll
        for (int g = 0; g < 4; ++g) {
          int c = ul * 4 + g;
          float s = 0.f;
#pragma unroll
          for (int w = 0; w < 8; ++w) s += sm.zsum[w][bb][c];
          z[g] = s + ld_sys(&hA[(size_t)bb * 3072 + 1024 + n0 + c]) + lstm_b[g * 512 + u];
        }
        int ci = bb * 512 + u;
        float cold = c_buf[ci];
        float c2 = sigf(z[1]) * cold + sigf(z[0]) * ftanh(z[2]);
        float h2 = sigf(z[3]) * ftanh(c2);
        c_buf[ci] = c2;
        st_sys(&h_buf[ci], h2);
        act_all[(size_t)(t * CB + bb) * 2560 + u] = h2;
      }
    }
    grid_barrier(bid, tid, ++ep);
  }
}

// ---------------- maxout (+ biases) ----------------
__global__ void maxout_kernel(const float* __restrict__ R, const float* __restrict__ br,
                              const float* __restrict__ bur, const float* __restrict__ bvr,
                              short* __restrict__ m_buf) {
  int idx = blockIdx.x * 256 + threadIdx.x;  // < 768*512
  int r = idx >> 9, j = idx & 511;
  int n0 = j * 2, n1 = j * 2 + 1;
  float v0 = R[(size_t)r * 1024 + n0] + br[n0] + bur[n0] + bvr[n0];
  float v1 = R[(size_t)r * 1024 + n1] + br[n1] + bur[n1] + bvr[n1];
  m_buf[(size_t)r * 512 + j] = f2bf(fmaxf(v0, v1));
}

// ---------------- logits GEMM: bf16 A,B -> f32 out + f32 bias ----------------
__global__ __launch_bounds__(256) void gemm_bf_kernel(
    const short* __restrict__ A, const short* __restrict__ BT,
    float* __restrict__ C, const float* __restrict__ bias, int N, int K) {
  const int lane = threadIdx.x & 63;
  const int wave = threadIdx.x >> 6;
  const int quad = lane >> 4;
  const int l16 = lane & 15;
  const int m_base = blockIdx.x * 64 + (wave & 1) * 32;
  const int n_base = blockIdx.y * 128 + (wave >> 1) * 64;

  floatx4 acc[2][4];
#pragma unroll
  for (int mi = 0; mi < 2; ++mi)
#pragma unroll
    for (int ni = 0; ni < 4; ++ni) acc[mi][ni] = (floatx4){0.f, 0.f, 0.f, 0.f};

  const short* a0p = A + (size_t)(m_base + l16) * K + quad * 8;
  const short* a1p = a0p + (size_t)16 * K;
  const short* b0p = BT + (size_t)(n_base + l16) * K + quad * 8;

  for (int k0 = 0; k0 < K; k0 += 32) {
    short8 a0 = *(const short8*)(a0p + k0);
    short8 a1 = *(const short8*)(a1p + k0);
#pragma unroll
    for (int ni = 0; ni < 4; ++ni) {
      short8 bb = *(const short8*)(b0p + (size_t)(ni * 16) * K + k0);
      acc[0][ni] = __builtin_amdgcn_mfma_f32_16x16x32_bf16(a0, bb, acc[0][ni], 0, 0, 0);
      acc[1][ni] = __builtin_amdgcn_mfma_f32_16x16x32_bf16(a1, bb, acc[1][ni], 0, 0, 0);
    }
  }
#pragma unroll
  for (int mi = 0; mi < 2; ++mi)
#pragma unroll
    for (int ni = 0; ni < 4; ++ni) {
      int col = n_base + ni * 16 + l16;
#pragma unroll
      for (int r = 0; r < 4; ++r) {
        int row = m_base + mi * 16 + quad * 4 + r;
        C[(size_t)row * N + col] = acc[mi][ni][r] + bias[col];
      }
    }
}

// ---------------- launch ----------------
extern "C" void kernel_launch(void* const* d_in, const int* in_sizes, int n_in,
                              void* d_out, int out_size, void* d_ws, size_t ws_size,
                              hipStream_t stream) {
  const float* bq     = (const float*)d_in[0];
  const float* facts  = (const float*)d_in[1];
  const int*   target = (const int*)d_in[2];
  const float* emb    = (const float*)d_in[4];
  const float* lstm_k = (const float*)d_in[5];
  const float* lstm_r = (const float*)d_in[6];
  const float* lstm_b = (const float*)d_in[7];
  const float* Wq1 = (const float*)d_in[8];
  const float* Wq2 = (const float*)d_in[9];
  const float* vq  = (const float*)d_in[10];
  const float* Wf1 = (const float*)d_in[11];
  const float* Wf2 = (const float*)d_in[12];
  const float* vf  = (const float*)d_in[13];
  const float* Wr  = (const float*)d_in[14];
  const float* br  = (const float*)d_in[15];
  const float* Ur  = (const float*)d_in[16];
  const float* bur = (const float*)d_in[17];
  const float* Vr  = (const float*)d_in[18];
  const float* bvr = (const float*)d_in[19];
  const float* Wy  = (const float*)d_in[20];
  const float* by  = (const float*)d_in[21];

  char* ws = (char*)d_ws;
  float* f_proj  = (float*)(ws + OFF_FPROJ);
  float* q_proj  = (float*)(ws + OFF_QPROJ);
  short* BTAh    = (short*)(ws + OFF_BTA);
  short* BTAl    = BTAh + (size_t)3072 * 512;
  short* BTCh    = (short*)(ws + OFF_BTC);
  short* BTCl    = BTCh + (size_t)2048 * 1536;
  float* act_all = (float*)(ws + OFF_ACT);
  short* BTW1h   = (short*)(ws + OFF_ACT);            // setup-phase alias (dies before gather_prev)
  short* BTW1l   = BTW1h + (size_t)512 * 512;
  float* hA      = (float*)(ws + OFF_HA);
  float* h_buf   = (float*)(ws + OFF_H);
  float* xq      = (float*)(ws + OFF_XQ);
  float* c_buf   = (float*)(ws + OFF_C);
  float* fs_buf  = (float*)(ws + OFF_FS);
  short* BTY     = (short*)(ws + OFF_BTY);
  short* BTRh    = (short*)(ws + OFF_BTR);
  short* BTRl    = BTRh + (size_t)1024 * 2560;
  float* R_buf   = (float*)(ws + OFF_RBUF);
  short* m_buf   = (short*)(ws + OFF_MBUF);
  float* out     = (float*)d_out;

  auto TS = [&](const float* src, int sld, int srow0, short* dh, short* dl, int dld,
                int drow0, int dcol0, int NR, int NK, int perm) {
    transpose_split_kernel<<<dim3(NR / 64, NK / 64), 256, 0, stream>>>(
        src, sld, srow0, dh, dl, dld, drow0, dcol0, perm);
  };

  // --- persistent transposed + pre-split weights (bf16 hi/lo) ---
  TS(Wq2, 512, 0, BTAh, BTAl, 512, 0, 0, 512, 512, 0);
  TS(Wf2, 512, 0, BTAh, BTAl, 512, 512, 0, 512, 512, 0);
  TS(lstm_r, 2048, 0, BTAh, BTAl, 512, 1024, 0, 2048, 512, 1);         // gate-permuted
  TS(lstm_k, 2048, 512, BTCh, BTCl, 1536, 0, 0, 2048, 512, 1);         // fvec K-part, permuted
  TS(lstm_k, 2048, 1024, BTCh, BTCl, 1536, 0, 512, 2048, 512, 1);      // qvec K-part, permuted
  TS(lstm_k, 2048, 0, BTCh, BTCl, 1536, 0, 1024, 2048, 512, 1);        // prev K-part, permuted

  // --- hoisted projections (BTW1 aliases act_all; used before gather_prev) ---
  TS(Wq1, 512, 0, BTW1h, BTW1l, 512, 0, 0, 512, 512, 0);
  gemm_bsw_kernel<<<dim3(32, 1), 256, 0, stream>>>(bq, BTW1h, BTW1l, q_proj, 512, 512);
  TS(Wf1, 512, 0, BTW1h, BTW1l, 512, 0, 0, 512, 512, 0);
  gemm_bsw_kernel<<<dim3(640, 1), 256, 0, stream>>>(facts, BTW1h, BTW1l, f_proj, 512, 512);

  // --- init recurrent state + barrier cells + prev tokens ---
  init_kernel<<<64, 256, 0, stream>>>(h_buf, c_buf);
  gather_prev_kernel<<<768, 256, 0, stream>>>(target, emb, act_all);

  // --- recurrence: persistent kernel, fence-free flag barriers ---
  recurrence_kernel<<<NBLK, 512, 0, stream>>>(f_proj, q_proj, BTAh, BTAl, BTCh, BTCl,
                                              facts, bq, vq, vf, lstm_b,
                                              hA, h_buf, c_buf, xq, fs_buf, act_all);

  // --- end-stage weights into dead regions ---
  TS(Wr, 1024, 0, BTRh, BTRl, 2560, 0, 0, 1024, 512, 0);
  TS(Ur, 1024, 0, BTRh, BTRl, 2560, 0, 512, 1024, 1536, 0);
  TS(Vr, 1024, 0, BTRh, BTRl, 2560, 0, 2048, 1024, 512, 0);
  transpose_f2b_kernel<<<dim3(500, 8), 256, 0, stream>>>(Wy, 32000, BTY, 512);

  // --- batched readout + maxout + logits ---
  gemm_bsw_kernel<<<dim3(24, 2), 256, 0, stream>>>(act_all, BTRh, BTRl, R_buf, 1024, 2560);
  maxout_kernel<<<1536, 256, 0, stream>>>(R_buf, br, bur, bvr, m_buf);
  gemm_bf_kernel<<<dim3(12, 250), 256, 0, stream>>>(m_buf, BTY, out, by, 32000, 512);
}